// Round 1
// baseline (607.186 us; speedup 1.0000x reference)
//
#include <hip/hip_runtime.h>
#include <cstdint>

// Problem constants (from reference setup_inputs)
#define BATCH   16
#define CCH     512
#define DD      32
#define NCODES  16384
#define HWSZ    1024            // 32*32
#define P_TOTAL 16384           // BATCH * HWSZ
#define NCHUNK  16
#define CHUNK   (NCODES / NCHUNK)   // 1024

// ---------------------------------------------------------------------------
// Kernel A: z[p][d] = sum_c enc[b][c][hw] * proj_w[d][c] + proj_b[d]
// block: 256 thr = 64 positions (hw contiguous, one b) x 4 d-groups of 8
// enc loads coalesced along hw; proj_w/proj_b wave-uniform -> s_load.
// Also emits invz[p] = 1/max(||z_p||, eps).
// ---------------------------------------------------------------------------
__global__ __launch_bounds__(256) void proj_kernel(
    const float* __restrict__ enc, const float* __restrict__ pw,
    const float* __restrict__ pb, float* __restrict__ z,
    float* __restrict__ invz)
{
    const int t    = threadIdx.x;
    const int hw_l = t & 63;
    const int dg   = t >> 6;            // 0..3 (wave-uniform)
    const int p0   = blockIdx.x * 64;
    const int b    = p0 >> 10;
    const int hw   = (p0 & 1023) + hw_l;
    const float* encb = enc + (size_t)b * (CCH * HWSZ) + hw;

    float acc[8];
#pragma unroll
    for (int j = 0; j < 8; j++) acc[j] = 0.f;

#pragma unroll 4
    for (int c = 0; c < CCH; c++) {
        float ev = encb[(size_t)c * HWSZ];          // coalesced across lanes
#pragma unroll
        for (int j = 0; j < 8; j++)                  // pw index wave-uniform
            acc[j] = fmaf(ev, pw[(dg * 8 + j) * CCH + c], acc[j]);
    }

    const int p = p0 + hw_l;
    float ssq = 0.f;
#pragma unroll
    for (int j = 0; j < 8; j++) {
        const int d = dg * 8 + j;
        const float v = acc[j] + pb[d];
        z[(size_t)p * DD + d] = v;
        ssq = fmaf(v, v, ssq);
    }

    __shared__ float red[4][64];
    red[dg][hw_l] = ssq;
    __syncthreads();
    if (t < 64) {
        const float tot = red[0][t] + red[1][t] + red[2][t] + red[3][t];
        invz[p0 + t] = 1.f / fmaxf(sqrtf(tot), 1e-6f);
    }
}

// ---------------------------------------------------------------------------
// Kernel B: en[r][:] = emb[r][:] / max(||emb[r]||, eps)   (row-normalized codes)
// ---------------------------------------------------------------------------
__global__ __launch_bounds__(256) void enorm_kernel(
    const float* __restrict__ e, float* __restrict__ en)
{
    const int r = blockIdx.x * 256 + threadIdx.x;
    const float4* src = reinterpret_cast<const float4*>(e + (size_t)r * DD);
    float4 v[8];
    float ssq = 0.f;
#pragma unroll
    for (int q = 0; q < 8; q++) {
        v[q] = src[q];
        ssq += v[q].x * v[q].x + v[q].y * v[q].y + v[q].z * v[q].z + v[q].w * v[q].w;
    }
    const float inv = 1.f / fmaxf(sqrtf(ssq), 1e-6f);
    float4* dst = reinterpret_cast<float4*>(en + (size_t)r * DD);
#pragma unroll
    for (int q = 0; q < 8; q++) {
        float4 o;
        o.x = v[q].x * inv; o.y = v[q].y * inv;
        o.z = v[q].z * inv; o.w = v[q].w * inv;
        dst[q] = o;
    }
}

// ---------------------------------------------------------------------------
// Kernel C: per-position argmax_n  z_p . en_n  over one chunk of codes.
// lane <-> position (z in 32 VGPRs), code row wave-uniform -> s_load, so the
// inner loop is 32 v_fma (SGPR operand) + cmp/cndmask per code.
// Strict > with ascending n == numpy first-occurrence tie-break.
// ---------------------------------------------------------------------------
__global__ __launch_bounds__(256) void argmax_kernel(
    const float* __restrict__ z, const float* __restrict__ en,
    float* __restrict__ pval, int* __restrict__ pidx)
{
    const int pblk  = blockIdx.x & 63;
    const int chunk = blockIdx.x >> 6;
    const int p     = pblk * 256 + threadIdx.x;

    float zr[32];
    const float4* zsrc = reinterpret_cast<const float4*>(z + (size_t)p * DD);
#pragma unroll
    for (int q = 0; q < 8; q++) {
        const float4 v = zsrc[q];
        zr[q * 4 + 0] = v.x; zr[q * 4 + 1] = v.y;
        zr[q * 4 + 2] = v.z; zr[q * 4 + 3] = v.w;
    }

    float best = -1e30f;
    int   bidx = 0;
    const int n0 = chunk * CHUNK;
#pragma unroll 2
    for (int nn = 0; nn < CHUNK; nn++) {
        const int n = n0 + nn;
        const float4* e4 = reinterpret_cast<const float4*>(en + (size_t)n * DD);
        float s0 = 0.f, s1 = 0.f, s2 = 0.f, s3 = 0.f;   // 4 dep chains
#pragma unroll
        for (int q = 0; q < 8; q++) {
            const float4 ev = e4[q];                     // wave-uniform -> SGPRs
            s0 = fmaf(zr[q * 4 + 0], ev.x, s0);
            s1 = fmaf(zr[q * 4 + 1], ev.y, s1);
            s2 = fmaf(zr[q * 4 + 2], ev.z, s2);
            s3 = fmaf(zr[q * 4 + 3], ev.w, s3);
        }
        const float s = (s0 + s1) + (s2 + s3);
        if (s > best) { best = s; bidx = n; }
    }
    pval[chunk * P_TOTAL + p] = best;
    pidx[chunk * P_TOTAL + p] = bidx;
}

// ---------------------------------------------------------------------------
// Kernel D: combine chunk partials (ascending chunk order keeps lowest index
// on ties), histogram via atomics, quantization-loss partial sum.
// ---------------------------------------------------------------------------
__global__ __launch_bounds__(256) void combine_kernel(
    const float* __restrict__ pval, const int* __restrict__ pidx,
    const float* __restrict__ z, const float* __restrict__ invz,
    const float* __restrict__ en,
    int* __restrict__ idx, int* __restrict__ hist, float* __restrict__ lossAcc)
{
    const int p = blockIdx.x * 256 + threadIdx.x;
    float best = -1e30f;
    int   bi   = 0;
#pragma unroll
    for (int k = 0; k < NCHUNK; k++) {
        const float v = pval[k * P_TOTAL + p];
        const int   i = pidx[k * P_TOTAL + p];
        if (v > best) { best = v; bi = i; }
    }
    idx[p] = bi;
    atomicAdd(&hist[bi], 1);

    const float iv = invz[p];
    const float4* zsrc = reinterpret_cast<const float4*>(z + (size_t)p * DD);
    const float4* esrc = reinterpret_cast<const float4*>(en + (size_t)bi * DD);
    float ls = 0.f;
#pragma unroll
    for (int q = 0; q < 8; q++) {
        const float4 zv = zsrc[q];
        const float4 ev = esrc[q];
        const float dx = zv.x * iv - ev.x;
        const float dy = zv.y * iv - ev.y;
        const float dz = zv.z * iv - ev.z;
        const float dw = zv.w * iv - ev.w;
        ls += dx * dx + dy * dy + dz * dz + dw * dw;
    }
    __shared__ float red[256];
    red[threadIdx.x] = ls;
    __syncthreads();
    for (int s = 128; s > 0; s >>= 1) {
        if (threadIdx.x < s) red[threadIdx.x] += red[threadIdx.x + s];
        __syncthreads();
    }
    if (threadIdx.x == 0) atomicAdd(lossAcc, red[0]);
}

// ---------------------------------------------------------------------------
// Kernel E: out[b][c][hw] = sum_d en[idx[p]][d] * exp_w[c][d] + exp_b[c]
// block: 64 positions x all 512 c (4 wave-groups of 128 c each).
// latents staged in LDS (pad 33 -> conflict-free), exp_w wave-uniform s_load,
// stores coalesced along hw.
// ---------------------------------------------------------------------------
__global__ __launch_bounds__(256) void expand_kernel(
    const int* __restrict__ idx, const float* __restrict__ en,
    const float* __restrict__ ew, const float* __restrict__ eb,
    float* __restrict__ out)
{
    const int t   = threadIdx.x;
    const int p0  = blockIdx.x * 64;
    const int b   = p0 >> 10;
    const int hw0 = p0 & 1023;

    __shared__ float lat[64 * 33];
    for (int i = t; i < 64 * DD; i += 256) {
        const int pl = i >> 5, d = i & 31;
        lat[pl * 33 + d] = en[(size_t)idx[p0 + pl] * DD + d];
    }
    __syncthreads();

    const int hw_l = t & 63;
    const int cg   = t >> 6;        // wave-uniform
    float lr[32];
#pragma unroll
    for (int d = 0; d < DD; d++) lr[d] = lat[hw_l * 33 + d];

    float* outb = out + (size_t)b * (CCH * HWSZ) + hw0 + hw_l;
    for (int k = 0; k < 128; k++) {
        const int c = cg * 128 + k;
        const float* ewc = ew + (size_t)c * DD;      // wave-uniform -> SGPRs
        float s0 = 0.f, s1 = 0.f, s2 = 0.f, s3 = 0.f;
#pragma unroll
        for (int d = 0; d < DD; d += 4) {
            s0 = fmaf(lr[d + 0], ewc[d + 0], s0);
            s1 = fmaf(lr[d + 1], ewc[d + 1], s1);
            s2 = fmaf(lr[d + 2], ewc[d + 2], s2);
            s3 = fmaf(lr[d + 3], ewc[d + 3], s3);
        }
        outb[(size_t)c * HWSZ] = (s0 + s1) + (s2 + s3) + eb[c];
    }
}

// ---------------------------------------------------------------------------
// Kernel F: perplexity from histogram + finalize loss scalar.
// ---------------------------------------------------------------------------
__global__ __launch_bounds__(256) void final_kernel(
    const int* __restrict__ hist, const float* __restrict__ lossAcc,
    float* __restrict__ out_scalars)
{
    __shared__ float red[256];
    float h = 0.f;
    for (int i = threadIdx.x; i < NCODES; i += 256) {
        const float u = (float)hist[i] * (1.f / (float)P_TOTAL);
        h -= u * logf(u + 1e-6f);
    }
    red[threadIdx.x] = h;
    __syncthreads();
    for (int s = 128; s > 0; s >>= 1) {
        if (threadIdx.x < s) red[threadIdx.x] += red[threadIdx.x + s];
        __syncthreads();
    }
    if (threadIdx.x == 0) {
        out_scalars[0] = lossAcc[0] * (1.f / (float)(P_TOTAL * DD));  // mean
        out_scalars[1] = expf(red[0]);
    }
}

// ---------------------------------------------------------------------------
// Workspace layout (bytes):
//   z      @ 0        : 16384*32*4 = 2,097,152
//   invz   @ 2097152  : 16384*4    =    65,536
//   en     @ 2162688  : 16384*32*4 = 2,097,152
//   pval   @ 4259840  : 16*16384*4 = 1,048,576
//   pidx   @ 5308416  : 16*16384*4 = 1,048,576
//   idx    @ 6356992  : 16384*4    =    65,536
//   hist   @ 6422528  : 16384*4    =    65,536
//   loss   @ 6488064  : 4                      (total ~6.5 MB)
// ---------------------------------------------------------------------------
extern "C" void kernel_launch(void* const* d_in, const int* in_sizes, int n_in,
                              void* d_out, int out_size, void* d_ws, size_t ws_size,
                              hipStream_t stream)
{
    const float* enc = (const float*)d_in[0];   // [16,512,32,32]
    const float* emb = (const float*)d_in[1];   // [16384,32]
    const float* pw  = (const float*)d_in[2];   // [32,512]
    const float* pb  = (const float*)d_in[3];   // [32]
    const float* ew  = (const float*)d_in[4];   // [512,32]
    const float* eb  = (const float*)d_in[5];   // [512]
    float* out = (float*)d_out;                 // 8388608 + loss + perplexity

    char* ws = (char*)d_ws;
    float* z       = (float*)(ws + 0);
    float* invz    = (float*)(ws + 2097152);
    float* en      = (float*)(ws + 2162688);
    float* pval    = (float*)(ws + 4259840);
    int*   pidx    = (int*)  (ws + 5308416);
    int*   idx     = (int*)  (ws + 6356992);
    int*   hist    = (int*)  (ws + 6422528);
    float* lossAcc = (float*)(ws + 6488064);

    // hist + lossAcc are contiguous: zero both in one async memset.
    hipMemsetAsync(hist, 0, NCODES * 4 + 4, stream);

    proj_kernel   <<<P_TOTAL / 64, 256, 0, stream>>>(enc, pw, pb, z, invz);
    enorm_kernel  <<<NCODES / 256, 256, 0, stream>>>(emb, en);
    argmax_kernel <<<64 * NCHUNK, 256, 0, stream>>>(z, en, pval, pidx);
    combine_kernel<<<P_TOTAL / 256, 256, 0, stream>>>(pval, pidx, z, invz, en,
                                                      idx, hist, lossAcc);
    expand_kernel <<<P_TOTAL / 64, 256, 0, stream>>>(idx, en, ew, eb, out);
    final_kernel  <<<1, 256, 0, stream>>>(hist, lossAcc, out + 8388608);
}

// Round 2
// 492.049 us; speedup vs baseline: 1.2340x; 1.2340x over previous
//
#include <hip/hip_runtime.h>
#include <cstdint>

// Problem constants (from reference setup_inputs)
#define BATCH   16
#define CCH     512
#define DD      32
#define NCODES  16384
#define HWSZ    1024            // 32*32
#define P_TOTAL 16384           // BATCH * HWSZ
#define NCHUNK  64
#define CHUNK   (NCODES / NCHUNK)   // 256

// ---------------------------------------------------------------------------
// Kernel A: z[p][d] = sum_c enc[b][c][hw] * proj_w[d][c] + proj_b[d]
// block: 256 thr = 64 positions (hw contiguous, one b) x 4 d-groups of 8.
// c-loop batched 8-wide: 8 outstanding HBM loads per wave to hide ~900 cyc
// miss latency at only 4 waves/CU. pw/pb wave-uniform -> s_load.
// Also emits invz[p] = 1/max(||z_p||, eps).
// ---------------------------------------------------------------------------
__global__ __launch_bounds__(256) void proj_kernel(
    const float* __restrict__ enc, const float* __restrict__ pw,
    const float* __restrict__ pb, float* __restrict__ z,
    float* __restrict__ invz)
{
    const int t    = threadIdx.x;
    const int hw_l = t & 63;
    const int dg   = t >> 6;            // 0..3 (wave-uniform)
    const int p0   = blockIdx.x * 64;
    const int b    = p0 >> 10;
    const int hw   = (p0 & 1023) + hw_l;
    const float* encb = enc + (size_t)b * (CCH * HWSZ) + hw;

    float acc[8];
#pragma unroll
    for (int j = 0; j < 8; j++) acc[j] = 0.f;

    for (int c0 = 0; c0 < CCH; c0 += 8) {
        float ev[8];
#pragma unroll
        for (int u = 0; u < 8; u++)                  // 8 loads issued back-to-back
            ev[u] = encb[(size_t)(c0 + u) * HWSZ];
#pragma unroll
        for (int u = 0; u < 8; u++)
#pragma unroll
            for (int j = 0; j < 8; j++)              // pw index wave-uniform
                acc[j] = fmaf(ev[u], pw[(dg * 8 + j) * CCH + c0 + u], acc[j]);
    }

    const int p = p0 + hw_l;
    float ssq = 0.f;
#pragma unroll
    for (int j = 0; j < 8; j++) {
        const int d = dg * 8 + j;
        const float v = acc[j] + pb[d];
        z[(size_t)p * DD + d] = v;
        ssq = fmaf(v, v, ssq);
    }

    __shared__ float red[4][64];
    red[dg][hw_l] = ssq;
    __syncthreads();
    if (t < 64) {
        const float tot = red[0][t] + red[1][t] + red[2][t] + red[3][t];
        invz[p0 + t] = 1.f / fmaxf(sqrtf(tot), 1e-6f);
    }
}

// ---------------------------------------------------------------------------
// Kernel B: en[r][:] = emb[r][:] / max(||emb[r]||, eps)   (row-normalized codes)
// ---------------------------------------------------------------------------
__global__ __launch_bounds__(256) void enorm_kernel(
    const float* __restrict__ e, float* __restrict__ en)
{
    const int r = blockIdx.x * 256 + threadIdx.x;
    const float4* src = reinterpret_cast<const float4*>(e + (size_t)r * DD);
    float4 v[8];
    float ssq = 0.f;
#pragma unroll
    for (int q = 0; q < 8; q++) {
        v[q] = src[q];
        ssq += v[q].x * v[q].x + v[q].y * v[q].y + v[q].z * v[q].z + v[q].w * v[q].w;
    }
    const float inv = 1.f / fmaxf(sqrtf(ssq), 1e-6f);
    float4* dst = reinterpret_cast<float4*>(en + (size_t)r * DD);
#pragma unroll
    for (int q = 0; q < 8; q++) {
        float4 o;
        o.x = v[q].x * inv; o.y = v[q].y * inv;
        o.z = v[q].z * inv; o.w = v[q].w * inv;
        dst[q] = o;
    }
}

// ---------------------------------------------------------------------------
// Kernel C: per-position argmax_n  z_p . en_n  over one chunk of codes.
// 4 positions per thread: each wave-uniform code row (s_load, SGPRs) feeds
// 128 FMAs across 16 independent dep chains -> ~60% duty/wave; 1024 blocks
// = 16 waves/CU so the VALU pipe saturates.
// Strict > with ascending n == numpy first-occurrence tie-break.
// ---------------------------------------------------------------------------
__global__ __launch_bounds__(256) void argmax_kernel(
    const float* __restrict__ z, const float* __restrict__ en,
    float* __restrict__ pval, int* __restrict__ pidx)
{
    const int pblk  = blockIdx.x & 15;      // 16 position blocks of 1024
    const int chunk = blockIdx.x >> 4;      // 64 chunks of 256 codes
    const int pbase = pblk * 1024 + threadIdx.x;

    float zr[4][32];
#pragma unroll
    for (int k = 0; k < 4; k++) {
        const float4* zsrc =
            reinterpret_cast<const float4*>(z + (size_t)(pbase + k * 256) * DD);
#pragma unroll
        for (int q = 0; q < 8; q++) {
            const float4 v = zsrc[q];
            zr[k][q * 4 + 0] = v.x; zr[k][q * 4 + 1] = v.y;
            zr[k][q * 4 + 2] = v.z; zr[k][q * 4 + 3] = v.w;
        }
    }

    float best[4] = {-1e30f, -1e30f, -1e30f, -1e30f};
    int   bidx[4] = {0, 0, 0, 0};
    const int n0 = chunk * CHUNK;
    for (int nn = 0; nn < CHUNK; nn++) {
        const int n = n0 + nn;
        const float4* e4 = reinterpret_cast<const float4*>(en + (size_t)n * DD);
        float4 ev[8];
#pragma unroll
        for (int q = 0; q < 8; q++) ev[q] = e4[q];   // wave-uniform -> SGPRs

        float s0[4], s1[4], s2[4], s3[4];
#pragma unroll
        for (int k = 0; k < 4; k++) { s0[k] = s1[k] = s2[k] = s3[k] = 0.f; }
#pragma unroll
        for (int q = 0; q < 8; q++) {
#pragma unroll
            for (int k = 0; k < 4; k++) {
                s0[k] = fmaf(zr[k][q * 4 + 0], ev[q].x, s0[k]);
                s1[k] = fmaf(zr[k][q * 4 + 1], ev[q].y, s1[k]);
                s2[k] = fmaf(zr[k][q * 4 + 2], ev[q].z, s2[k]);
                s3[k] = fmaf(zr[k][q * 4 + 3], ev[q].w, s3[k]);
            }
        }
#pragma unroll
        for (int k = 0; k < 4; k++) {
            const float s = (s0[k] + s1[k]) + (s2[k] + s3[k]);
            if (s > best[k]) { best[k] = s; bidx[k] = n; }
        }
    }
#pragma unroll
    for (int k = 0; k < 4; k++) {
        pval[chunk * P_TOTAL + pbase + k * 256] = best[k];
        pidx[chunk * P_TOTAL + pbase + k * 256] = bidx[k];
    }
}

// ---------------------------------------------------------------------------
// Kernel D: combine chunk partials (ascending chunk order keeps lowest index
// on ties), histogram via atomics, quantization-loss partial sum.
// ---------------------------------------------------------------------------
__global__ __launch_bounds__(256) void combine_kernel(
    const float* __restrict__ pval, const int* __restrict__ pidx,
    const float* __restrict__ z, const float* __restrict__ invz,
    const float* __restrict__ en,
    int* __restrict__ idx, int* __restrict__ hist, float* __restrict__ lossAcc)
{
    const int p = blockIdx.x * 256 + threadIdx.x;
    float best = -1e30f;
    int   bi   = 0;
#pragma unroll 8
    for (int k = 0; k < NCHUNK; k++) {
        const float v = pval[k * P_TOTAL + p];
        const int   i = pidx[k * P_TOTAL + p];
        if (v > best) { best = v; bi = i; }
    }
    idx[p] = bi;
    atomicAdd(&hist[bi], 1);

    const float iv = invz[p];
    const float4* zsrc = reinterpret_cast<const float4*>(z + (size_t)p * DD);
    const float4* esrc = reinterpret_cast<const float4*>(en + (size_t)bi * DD);
    float ls = 0.f;
#pragma unroll
    for (int q = 0; q < 8; q++) {
        const float4 zv = zsrc[q];
        const float4 ev = esrc[q];
        const float dx = zv.x * iv - ev.x;
        const float dy = zv.y * iv - ev.y;
        const float dz = zv.z * iv - ev.z;
        const float dw = zv.w * iv - ev.w;
        ls += dx * dx + dy * dy + dz * dz + dw * dw;
    }
    __shared__ float red[256];
    red[threadIdx.x] = ls;
    __syncthreads();
    for (int s = 128; s > 0; s >>= 1) {
        if (threadIdx.x < s) red[threadIdx.x] += red[threadIdx.x + s];
        __syncthreads();
    }
    if (threadIdx.x == 0) atomicAdd(lossAcc, red[0]);
}

// ---------------------------------------------------------------------------
// Kernel E: out[b][c][hw] = sum_d en[idx[p]][d] * exp_w[c][d] + exp_b[c]
// block: 64 positions x all 512 c (4 wave-groups of 128 c each).
// latents staged in LDS (pad 33 -> conflict-free), exp_w wave-uniform s_load,
// stores coalesced along hw. c-loop unrolled 4 to batch s_loads/stores.
// ---------------------------------------------------------------------------
__global__ __launch_bounds__(256) void expand_kernel(
    const int* __restrict__ idx, const float* __restrict__ en,
    const float* __restrict__ ew, const float* __restrict__ eb,
    float* __restrict__ out)
{
    const int t   = threadIdx.x;
    const int p0  = blockIdx.x * 64;
    const int b   = p0 >> 10;
    const int hw0 = p0 & 1023;

    __shared__ float lat[64 * 33];
    for (int i = t; i < 64 * DD; i += 256) {
        const int pl = i >> 5, d = i & 31;
        lat[pl * 33 + d] = en[(size_t)idx[p0 + pl] * DD + d];
    }
    __syncthreads();

    const int hw_l = t & 63;
    const int cg   = t >> 6;        // wave-uniform
    float lr[32];
#pragma unroll
    for (int d = 0; d < DD; d++) lr[d] = lat[hw_l * 33 + d];

    float* outb = out + (size_t)b * (CCH * HWSZ) + hw0 + hw_l;
#pragma unroll 4
    for (int k = 0; k < 128; k++) {
        const int c = cg * 128 + k;
        const float* ewc = ew + (size_t)c * DD;      // wave-uniform -> SGPRs
        float s0 = 0.f, s1 = 0.f, s2 = 0.f, s3 = 0.f;
#pragma unroll
        for (int d = 0; d < DD; d += 4) {
            s0 = fmaf(lr[d + 0], ewc[d + 0], s0);
            s1 = fmaf(lr[d + 1], ewc[d + 1], s1);
            s2 = fmaf(lr[d + 2], ewc[d + 2], s2);
            s3 = fmaf(lr[d + 3], ewc[d + 3], s3);
        }
        outb[(size_t)c * HWSZ] = (s0 + s1) + (s2 + s3) + eb[c];
    }
}

// ---------------------------------------------------------------------------
// Kernel F: perplexity from histogram + finalize loss scalar.
// ---------------------------------------------------------------------------
__global__ __launch_bounds__(256) void final_kernel(
    const int* __restrict__ hist, const float* __restrict__ lossAcc,
    float* __restrict__ out_scalars)
{
    __shared__ float red[256];
    float h = 0.f;
    for (int i = threadIdx.x; i < NCODES; i += 256) {
        const float u = (float)hist[i] * (1.f / (float)P_TOTAL);
        h -= u * logf(u + 1e-6f);
    }
    red[threadIdx.x] = h;
    __syncthreads();
    for (int s = 128; s > 0; s >>= 1) {
        if (threadIdx.x < s) red[threadIdx.x] += red[threadIdx.x + s];
        __syncthreads();
    }
    if (threadIdx.x == 0) {
        out_scalars[0] = lossAcc[0] * (1.f / (float)(P_TOTAL * DD));  // mean
        out_scalars[1] = expf(red[0]);
    }
}

// ---------------------------------------------------------------------------
// Workspace layout (bytes):
//   z      @ 0        : 16384*32*4 = 2,097,152
//   invz   @ 2097152  : 16384*4    =    65,536
//   en     @ 2162688  : 16384*32*4 = 2,097,152
//   pval   @ 4259840  : 64*16384*4 = 4,194,304
//   pidx   @ 8454144  : 64*16384*4 = 4,194,304
//   idx    @ 12648448 : 16384*4    =    65,536
//   hist   @ 12713984 : 16384*4    =    65,536
//   loss   @ 12779520 : 4                      (total ~12.8 MB)
// ---------------------------------------------------------------------------
extern "C" void kernel_launch(void* const* d_in, const int* in_sizes, int n_in,
                              void* d_out, int out_size, void* d_ws, size_t ws_size,
                              hipStream_t stream)
{
    const float* enc = (const float*)d_in[0];   // [16,512,32,32]
    const float* emb = (const float*)d_in[1];   // [16384,32]
    const float* pw  = (const float*)d_in[2];   // [32,512]
    const float* pb  = (const float*)d_in[3];   // [32]
    const float* ew  = (const float*)d_in[4];   // [512,32]
    const float* eb  = (const float*)d_in[5];   // [512]
    float* out = (float*)d_out;                 // 8388608 + loss + perplexity

    char* ws = (char*)d_ws;
    float* z       = (float*)(ws + 0);
    float* invz    = (float*)(ws + 2097152);
    float* en      = (float*)(ws + 2162688);
    float* pval    = (float*)(ws + 4259840);
    int*   pidx    = (int*)  (ws + 8454144);
    int*   idx     = (int*)  (ws + 12648448);
    int*   hist    = (int*)  (ws + 12713984);
    float* lossAcc = (float*)(ws + 12779520);

    // hist + lossAcc are contiguous: zero both in one async memset.
    hipMemsetAsync(hist, 0, NCODES * 4 + 4, stream);

    proj_kernel   <<<P_TOTAL / 64, 256, 0, stream>>>(enc, pw, pb, z, invz);
    enorm_kernel  <<<NCODES / 256, 256, 0, stream>>>(emb, en);
    argmax_kernel <<<16 * NCHUNK, 256, 0, stream>>>(z, en, pval, pidx);
    combine_kernel<<<P_TOTAL / 256, 256, 0, stream>>>(pval, pidx, z, invz, en,
                                                      idx, hist, lossAcc);
    expand_kernel <<<P_TOTAL / 64, 256, 0, stream>>>(idx, en, ew, eb, out);
    final_kernel  <<<1, 256, 0, stream>>>(hist, lossAcc, out + 8388608);
}

// Round 3
// 415.975 us; speedup vs baseline: 1.4597x; 1.1829x over previous
//
#include <hip/hip_runtime.h>
#include <cstdint>

// Problem constants (from reference setup_inputs)
#define BATCH   16
#define CCH     512
#define DD      32
#define NCODES  16384
#define HWSZ    1024            // 32*32
#define P_TOTAL 16384           // BATCH * HWSZ
#define NCHUNK  64
#define CHUNK   (NCODES / NCHUNK)   // 256

// ---------------------------------------------------------------------------
// Kernel A: partial projection. Grid 512 = 256 position-groups x 2 c-halves.
// zpart[ch][p][d] = sum_{c in half} enc[b][c][hw] * proj_w[d][c]
// block: 256 thr = 64 positions x 4 d-groups of 8; 16 loads in flight/wave
// (4 waves/CU x 16 x 256B = 16KB in flight -> HBM BW saturated).
// ---------------------------------------------------------------------------
__global__ __launch_bounds__(256) void proj_kernel(
    const float* __restrict__ enc, const float* __restrict__ pw,
    float* __restrict__ zpart)
{
    const int chalf = blockIdx.x & 1;
    const int pg    = blockIdx.x >> 1;
    const int t     = threadIdx.x;
    const int hw_l  = t & 63;
    const int dg    = t >> 6;           // 0..3 (wave-uniform)
    const int p0    = pg * 64;
    const int b     = p0 >> 10;
    const int hw    = (p0 & 1023) + hw_l;
    const int cbase = chalf * 256;
    const float* encb = enc + (size_t)b * (CCH * HWSZ) + (size_t)cbase * HWSZ + hw;

    float acc[8];
#pragma unroll
    for (int j = 0; j < 8; j++) acc[j] = 0.f;

    for (int c0 = 0; c0 < 256; c0 += 16) {
        float ev[16];
#pragma unroll
        for (int u = 0; u < 16; u++)                 // 16 loads in flight
            ev[u] = encb[(size_t)(c0 + u) * HWSZ];
#pragma unroll
        for (int u = 0; u < 16; u++)
#pragma unroll
            for (int j = 0; j < 8; j++)              // pw index wave-uniform
                acc[j] = fmaf(ev[u], pw[(dg * 8 + j) * CCH + cbase + c0 + u], acc[j]);
    }

    const int p = p0 + hw_l;
    float* zp = zpart + (size_t)chalf * (P_TOTAL * DD) + (size_t)p * DD + dg * 8;
#pragma unroll
    for (int j = 0; j < 8; j++) zp[j] = acc[j];
}

// ---------------------------------------------------------------------------
// Kernel A2: z = zpart[0] + zpart[1] + pb;  invz = 1/max(||z_p||, eps)
// One thread per position.
// ---------------------------------------------------------------------------
__global__ __launch_bounds__(256) void zmerge_kernel(
    const float* __restrict__ zpart, const float* __restrict__ pb,
    float* __restrict__ z, float* __restrict__ invz)
{
    const int p = blockIdx.x * 256 + threadIdx.x;
    const float4* a4 = reinterpret_cast<const float4*>(zpart + (size_t)p * DD);
    const float4* b4 = reinterpret_cast<const float4*>(zpart + (size_t)(P_TOTAL + p) * DD);
    const float4* pb4 = reinterpret_cast<const float4*>(pb);    // uniform -> s_load
    float4* z4 = reinterpret_cast<float4*>(z + (size_t)p * DD);
    float ssq = 0.f;
#pragma unroll
    for (int q = 0; q < 8; q++) {
        const float4 av = a4[q], bv = b4[q], pv = pb4[q];
        float4 o;
        o.x = av.x + bv.x + pv.x; o.y = av.y + bv.y + pv.y;
        o.z = av.z + bv.z + pv.z; o.w = av.w + bv.w + pv.w;
        z4[q] = o;
        ssq += o.x * o.x + o.y * o.y + o.z * o.z + o.w * o.w;
    }
    invz[p] = 1.f / fmaxf(sqrtf(ssq), 1e-6f);
}

// ---------------------------------------------------------------------------
// Kernel B: en[r][:] = emb[r][:] / max(||emb[r]||, eps)
// ---------------------------------------------------------------------------
__global__ __launch_bounds__(256) void enorm_kernel(
    const float* __restrict__ e, float* __restrict__ en)
{
    const int r = blockIdx.x * 256 + threadIdx.x;
    const float4* src = reinterpret_cast<const float4*>(e + (size_t)r * DD);
    float4 v[8];
    float ssq = 0.f;
#pragma unroll
    for (int q = 0; q < 8; q++) {
        v[q] = src[q];
        ssq += v[q].x * v[q].x + v[q].y * v[q].y + v[q].z * v[q].z + v[q].w * v[q].w;
    }
    const float inv = 1.f / fmaxf(sqrtf(ssq), 1e-6f);
    float4* dst = reinterpret_cast<float4*>(en + (size_t)r * DD);
#pragma unroll
    for (int q = 0; q < 8; q++) {
        float4 o;
        o.x = v[q].x * inv; o.y = v[q].y * inv;
        o.z = v[q].z * inv; o.w = v[q].w * inv;
        dst[q] = o;
    }
}

// ---------------------------------------------------------------------------
// Kernel C: per-position argmax over one 256-code chunk.
// K=2 positions/thread; launch_bounds(256,4) caps regs at 128 so zr stays in
// true VGPRs (R1: compiler pushed zr to AGPRs -> v_accvgpr traffic + 2
// waves/SIMD). 2048 blocks -> 5 waves/SIMD resident (VGPR-limited).
// Code row wave-uniform -> SGPRs. Strict > ascending n = numpy tie-break.
// ---------------------------------------------------------------------------
__global__ __launch_bounds__(256, 4) void argmax_kernel(
    const float* __restrict__ z, const float* __restrict__ en,
    float* __restrict__ pval, int* __restrict__ pidx)
{
    const int pblk  = blockIdx.x & 31;      // 32 position blocks of 512
    const int chunk = blockIdx.x >> 5;      // 64 chunks of 256 codes
    const int pbase = pblk * 512 + threadIdx.x;

    float zr[2][32];
#pragma unroll
    for (int k = 0; k < 2; k++) {
        const float4* zsrc =
            reinterpret_cast<const float4*>(z + (size_t)(pbase + k * 256) * DD);
#pragma unroll
        for (int q = 0; q < 8; q++) {
            const float4 v = zsrc[q];
            zr[k][q * 4 + 0] = v.x; zr[k][q * 4 + 1] = v.y;
            zr[k][q * 4 + 2] = v.z; zr[k][q * 4 + 3] = v.w;
        }
    }

    float best[2] = {-1e30f, -1e30f};
    int   bidx[2] = {0, 0};
    const int n0 = chunk * CHUNK;
#pragma unroll 2
    for (int nn = 0; nn < CHUNK; nn++) {
        const int n = n0 + nn;
        const float4* e4 = reinterpret_cast<const float4*>(en + (size_t)n * DD);
        float4 ev[8];
#pragma unroll
        for (int q = 0; q < 8; q++) ev[q] = e4[q];   // wave-uniform -> SGPRs

        float s0[2], s1[2], s2[2], s3[2];
#pragma unroll
        for (int k = 0; k < 2; k++) { s0[k] = s1[k] = s2[k] = s3[k] = 0.f; }
#pragma unroll
        for (int q = 0; q < 8; q++) {
#pragma unroll
            for (int k = 0; k < 2; k++) {
                s0[k] = fmaf(zr[k][q * 4 + 0], ev[q].x, s0[k]);
                s1[k] = fmaf(zr[k][q * 4 + 1], ev[q].y, s1[k]);
                s2[k] = fmaf(zr[k][q * 4 + 2], ev[q].z, s2[k]);
                s3[k] = fmaf(zr[k][q * 4 + 3], ev[q].w, s3[k]);
            }
        }
#pragma unroll
        for (int k = 0; k < 2; k++) {
            const float s = (s0[k] + s1[k]) + (s2[k] + s3[k]);
            if (s > best[k]) { best[k] = s; bidx[k] = n; }
        }
    }
#pragma unroll
    for (int k = 0; k < 2; k++) {
        pval[chunk * P_TOTAL + pbase + k * 256] = best[k];
        pidx[chunk * P_TOTAL + pbase + k * 256] = bidx[k];
    }
}

// ---------------------------------------------------------------------------
// Kernel D: combine chunk partials (ascending k keeps lowest index on ties),
// histogram via atomics, quantization-loss partial sum. 64-thr blocks so the
// grid (256 blocks) covers all CUs.
// ---------------------------------------------------------------------------
__global__ __launch_bounds__(64) void combine_kernel(
    const float* __restrict__ pval, const int* __restrict__ pidx,
    const float* __restrict__ z, const float* __restrict__ invz,
    const float* __restrict__ en,
    int* __restrict__ idx, int* __restrict__ hist, float* __restrict__ lossAcc)
{
    const int p = blockIdx.x * 64 + threadIdx.x;
    float best = -1e30f;
    int   bi   = 0;
#pragma unroll 8
    for (int k = 0; k < NCHUNK; k++) {
        const float v = pval[k * P_TOTAL + p];
        const int   i = pidx[k * P_TOTAL + p];
        if (v > best) { best = v; bi = i; }
    }
    idx[p] = bi;
    atomicAdd(&hist[bi], 1);

    const float iv = invz[p];
    const float4* zsrc = reinterpret_cast<const float4*>(z + (size_t)p * DD);
    const float4* esrc = reinterpret_cast<const float4*>(en + (size_t)bi * DD);
    float ls = 0.f;
#pragma unroll
    for (int q = 0; q < 8; q++) {
        const float4 zv = zsrc[q];
        const float4 ev = esrc[q];
        const float dx = zv.x * iv - ev.x;
        const float dy = zv.y * iv - ev.y;
        const float dz = zv.z * iv - ev.z;
        const float dw = zv.w * iv - ev.w;
        ls += dx * dx + dy * dy + dz * dz + dw * dw;
    }
    __shared__ float red[64];
    red[threadIdx.x] = ls;
    __syncthreads();
    for (int s = 32; s > 0; s >>= 1) {
        if (threadIdx.x < s) red[threadIdx.x] += red[threadIdx.x + s];
        __syncthreads();
    }
    if (threadIdx.x == 0) atomicAdd(lossAcc, red[0]);
}

// ---------------------------------------------------------------------------
// Kernel E: out[b][c][hw] = sum_d en[idx[p]][d] * exp_w[c][d] + exp_b[c]
// Grid 512 = 256 position-groups x 2 c-halves (2 blocks/CU). Block: 64
// positions x 256 c (4 waves x 64 c). latents in LDS (pad 33), exp_w
// wave-uniform s_load, stores coalesced along hw.
// ---------------------------------------------------------------------------
__global__ __launch_bounds__(256) void expand_kernel(
    const int* __restrict__ idx, const float* __restrict__ en,
    const float* __restrict__ ew, const float* __restrict__ eb,
    float* __restrict__ out)
{
    const int t     = threadIdx.x;
    const int chalf = blockIdx.x & 1;
    const int pg    = blockIdx.x >> 1;
    const int p0    = pg * 64;
    const int b     = p0 >> 10;
    const int hw0   = p0 & 1023;

    __shared__ float lat[64 * 33];
    for (int i = t; i < 64 * DD; i += 256) {
        const int pl = i >> 5, d = i & 31;
        lat[pl * 33 + d] = en[(size_t)idx[p0 + pl] * DD + d];
    }
    __syncthreads();

    const int hw_l = t & 63;
    const int cg   = t >> 6;        // wave-uniform
    float lr[32];
#pragma unroll
    for (int d = 0; d < DD; d++) lr[d] = lat[hw_l * 33 + d];

    float* outb = out + (size_t)b * (CCH * HWSZ) + hw0 + hw_l;
    const int c0 = chalf * 256 + cg * 64;
#pragma unroll 4
    for (int k = 0; k < 64; k++) {
        const int c = c0 + k;
        const float* ewc = ew + (size_t)c * DD;      // wave-uniform -> SGPRs
        float s0 = 0.f, s1 = 0.f, s2 = 0.f, s3 = 0.f;
#pragma unroll
        for (int d = 0; d < DD; d += 4) {
            s0 = fmaf(lr[d + 0], ewc[d + 0], s0);
            s1 = fmaf(lr[d + 1], ewc[d + 1], s1);
            s2 = fmaf(lr[d + 2], ewc[d + 2], s2);
            s3 = fmaf(lr[d + 3], ewc[d + 3], s3);
        }
        outb[(size_t)c * HWSZ] = (s0 + s1) + (s2 + s3) + eb[c];
    }
}

// ---------------------------------------------------------------------------
// Kernel F: perplexity from histogram + finalize loss scalar.
// ---------------------------------------------------------------------------
__global__ __launch_bounds__(256) void final_kernel(
    const int* __restrict__ hist, const float* __restrict__ lossAcc,
    float* __restrict__ out_scalars)
{
    __shared__ float red[256];
    float h = 0.f;
    for (int i = threadIdx.x; i < NCODES; i += 256) {
        const float u = (float)hist[i] * (1.f / (float)P_TOTAL);
        h -= u * logf(u + 1e-6f);
    }
    red[threadIdx.x] = h;
    __syncthreads();
    for (int s = 128; s > 0; s >>= 1) {
        if (threadIdx.x < s) red[threadIdx.x] += red[threadIdx.x + s];
        __syncthreads();
    }
    if (threadIdx.x == 0) {
        out_scalars[0] = lossAcc[0] * (1.f / (float)(P_TOTAL * DD));  // mean
        out_scalars[1] = expf(red[0]);
    }
}

// ---------------------------------------------------------------------------
// Workspace layout (bytes):
//   z      @ 0        : 16384*32*4 = 2,097,152
//   invz   @ 2097152  : 16384*4    =    65,536
//   en     @ 2162688  : 16384*32*4 = 2,097,152
//   pval   @ 4259840  : 64*16384*4 = 4,194,304   (aliased: zpart before argmax)
//   pidx   @ 8454144  : 64*16384*4 = 4,194,304
//   idx    @ 12648448 : 16384*4    =    65,536
//   hist   @ 12713984 : 16384*4    =    65,536
//   loss   @ 12779520 : 4                        (total ~12.8 MB)
// zpart (2*2MB) uses the pval region: proj writes it, zmerge consumes it,
// argmax overwrites it later — strictly ordered on one stream.
// ---------------------------------------------------------------------------
extern "C" void kernel_launch(void* const* d_in, const int* in_sizes, int n_in,
                              void* d_out, int out_size, void* d_ws, size_t ws_size,
                              hipStream_t stream)
{
    const float* enc = (const float*)d_in[0];   // [16,512,32,32]
    const float* emb = (const float*)d_in[1];   // [16384,32]
    const float* pw  = (const float*)d_in[2];   // [32,512]
    const float* pb  = (const float*)d_in[3];   // [32]
    const float* ew  = (const float*)d_in[4];   // [512,32]
    const float* eb  = (const float*)d_in[5];   // [512]
    float* out = (float*)d_out;                 // 8388608 + loss + perplexity

    char* ws = (char*)d_ws;
    float* z       = (float*)(ws + 0);
    float* invz    = (float*)(ws + 2097152);
    float* en      = (float*)(ws + 2162688);
    float* pval    = (float*)(ws + 4259840);
    float* zpart   = pval;                      // alias (dead before argmax)
    int*   pidx    = (int*)  (ws + 8454144);
    int*   idx     = (int*)  (ws + 12648448);
    int*   hist    = (int*)  (ws + 12713984);
    float* lossAcc = (float*)(ws + 12779520);

    // hist + lossAcc are contiguous: zero both in one async memset.
    hipMemsetAsync(hist, 0, NCODES * 4 + 4, stream);

    proj_kernel   <<<512, 256, 0, stream>>>(enc, pw, zpart);
    zmerge_kernel <<<P_TOTAL / 256, 256, 0, stream>>>(zpart, pb, z, invz);
    enorm_kernel  <<<NCODES / 256, 256, 0, stream>>>(emb, en);
    argmax_kernel <<<32 * NCHUNK, 256, 0, stream>>>(z, en, pval, pidx);
    combine_kernel<<<P_TOTAL / 64, 64, 0, stream>>>(pval, pidx, z, invz, en,
                                                    idx, hist, lossAcc);
    expand_kernel <<<512, 256, 0, stream>>>(idx, en, ew, eb, out);
    final_kernel  <<<1, 256, 0, stream>>>(hist, lossAcc, out + 8388608);
}

// Round 4
// 362.743 us; speedup vs baseline: 1.6739x; 1.1467x over previous
//
#include <hip/hip_runtime.h>
#include <cstdint>

// Problem constants (from reference setup_inputs)
#define BATCH   16
#define CCH     512
#define DD      32
#define NCODES  16384
#define HWSZ    1024            // 32*32
#define P_TOTAL 16384           // BATCH * HWSZ
#define NCHUNK  16
#define CHUNK   (NCODES / NCHUNK)   // 1024 codes per chunk

typedef _Float16 half8 __attribute__((ext_vector_type(8)));
typedef float    f32x4 __attribute__((ext_vector_type(4)));

union H8 { _Float16 h[8]; uint4 u; };
union L8 { uint4 u; half8 h; };

// f16 split row layout: row = 128 B = [32 f16 hi | 32 f16 lo], values scaled
// by 2^12 so lo-terms stay in f16 normal range (|z|<6 -> hi<24576<65504).
// sim accumulates at scale 2^24; argmax is scale-invariant.

// ---------------------------------------------------------------------------
// Kernel A: z[p][d] = sum_c enc[b][c][hw] * proj_w[d][c] + proj_b[d]
// block: 256 thr = 64 positions x 4 d-groups of 8; 16 loads in flight/wave.
// Epilogue: z fp32, invz, and zf16 split rows (hi|lo, scaled 2^12).
// ---------------------------------------------------------------------------
__global__ __launch_bounds__(256) void proj_kernel(
    const float* __restrict__ enc, const float* __restrict__ pw,
    const float* __restrict__ pb, float* __restrict__ z,
    float* __restrict__ invz, char* __restrict__ zf16)
{
    const int t    = threadIdx.x;
    const int hw_l = t & 63;
    const int dg   = t >> 6;            // 0..3 (wave-uniform)
    const int p0   = blockIdx.x * 64;
    const int b    = p0 >> 10;
    const int hw   = (p0 & 1023) + hw_l;
    const float* encb = enc + (size_t)b * (CCH * HWSZ) + hw;

    float acc[8];
#pragma unroll
    for (int j = 0; j < 8; j++) acc[j] = 0.f;

    for (int c0 = 0; c0 < CCH; c0 += 16) {
        float ev[16];
#pragma unroll
        for (int u = 0; u < 16; u++)                 // 16 loads in flight
            ev[u] = encb[(size_t)(c0 + u) * HWSZ];
#pragma unroll
        for (int u = 0; u < 16; u++)
#pragma unroll
            for (int j = 0; j < 8; j++)              // pw index wave-uniform
                acc[j] = fmaf(ev[u], pw[(dg * 8 + j) * CCH + c0 + u], acc[j]);
    }

    const int p = p0 + hw_l;
    float ssq = 0.f;
    H8 hi, lo;
#pragma unroll
    for (int j = 0; j < 8; j++) {
        const float v = acc[j] + pb[dg * 8 + j];
        z[(size_t)p * DD + dg * 8 + j] = v;
        ssq = fmaf(v, v, ssq);
        const float vs = v * 4096.f;
        const _Float16 h = (_Float16)vs;
        hi.h[j] = h;
        lo.h[j] = (_Float16)(vs - (float)h);
    }
    char* row = zf16 + (size_t)p * 128;
    *(uint4*)(row + dg * 16)      = hi.u;
    *(uint4*)(row + 64 + dg * 16) = lo.u;

    __shared__ float red[4][64];
    red[dg][hw_l] = ssq;
    __syncthreads();
    if (t < 64) {
        const float tot = red[0][t] + red[1][t] + red[2][t] + red[3][t];
        invz[p0 + t] = 1.f / fmaxf(sqrtf(tot), 1e-6f);
    }
}

// ---------------------------------------------------------------------------
// Kernel B: en[r] = emb[r]/max(||emb[r]||,eps) fp32 + ef16 split rows.
// ---------------------------------------------------------------------------
__global__ __launch_bounds__(256) void enorm_kernel(
    const float* __restrict__ e, float* __restrict__ en,
    char* __restrict__ ef16)
{
    const int r = blockIdx.x * 256 + threadIdx.x;
    const float4* src = reinterpret_cast<const float4*>(e + (size_t)r * DD);
    float4 v[8];
    float ssq = 0.f;
#pragma unroll
    for (int q = 0; q < 8; q++) {
        v[q] = src[q];
        ssq += v[q].x * v[q].x + v[q].y * v[q].y + v[q].z * v[q].z + v[q].w * v[q].w;
    }
    const float inv = 1.f / fmaxf(sqrtf(ssq), 1e-6f);
    float4* dst = reinterpret_cast<float4*>(en + (size_t)r * DD);
    char* row = ef16 + (size_t)r * 128;
#pragma unroll
    for (int q = 0; q < 8; q += 2) {                 // 8 values per iter
        H8 hi, lo;
#pragma unroll
        for (int u = 0; u < 2; u++) {
            float4 o;
            o.x = v[q + u].x * inv; o.y = v[q + u].y * inv;
            o.z = v[q + u].z * inv; o.w = v[q + u].w * inv;
            dst[q + u] = o;
            const float s[4] = {o.x * 4096.f, o.y * 4096.f, o.z * 4096.f, o.w * 4096.f};
#pragma unroll
            for (int j = 0; j < 4; j++) {
                const _Float16 h = (_Float16)s[j];
                hi.h[u * 4 + j] = h;
                lo.h[u * 4 + j] = (_Float16)(s[j] - (float)h);
            }
        }
        *(uint4*)(row + q * 8)      = hi.u;          // hi block: bytes [0,64)
        *(uint4*)(row + 64 + q * 8) = lo.u;          // lo block: bytes [64,128)
    }
}

// ---------------------------------------------------------------------------
// Kernel C: fused MFMA sims + argmax over one 1024-code chunk.
// Wave = 32 positions (2 B-frag pairs held in regs); A = code tiles streamed
// from L2. Per 16-code tile: 2 dwordx4 loads + 8 mfma_f32_16x16x32_f16 + 24
// VALU argmax epilogue. D layout: code=(lane>>4)*4+reg, pos=lane&15 ->
// argmax reg-local, then shfl_xor(16,32) with equal->lower-idx tie-break
// (matches numpy first-occurrence).
// ---------------------------------------------------------------------------
__global__ __launch_bounds__(256) void argmax_kernel(
    const char* __restrict__ zf16, const char* __restrict__ ef16,
    float* __restrict__ pval, int* __restrict__ pidx)
{
    const int w    = threadIdx.x >> 6;       // wave 0..3
    const int lane = threadIdx.x & 63;
    const int col  = lane & 15;
    const int quad = lane >> 4;
    const int pg    = blockIdx.x & 127;      // 128 position groups of 128
    const int chunk = blockIdx.x >> 7;       // 16 chunks of 1024 codes
    const int wp0   = pg * 128 + w * 32;     // wave position base

    // B fragments (z): pos-tile0 rows wp0+col, pos-tile1 rows wp0+16+col
    half8 b0h, b0l, b1h, b1l;
    {
        const char* r0 = zf16 + (size_t)(wp0 + col) * 128 + quad * 16;
        const char* r1 = r0 + 16 * 128;
        L8 a; a.u = *(const uint4*)(r0);       b0h = a.h;
        L8 b; b.u = *(const uint4*)(r0 + 64);  b0l = b.h;
        L8 c; c.u = *(const uint4*)(r1);       b1h = c.h;
        L8 d; d.u = *(const uint4*)(r1 + 64);  b1l = d.h;
    }

    const int n0 = chunk * CHUNK;
    const char* abase = ef16 + (size_t)(n0 + col) * 128 + quad * 16;

    float best0 = -3e38f, best1 = -3e38f;
    int   bi0 = 0, bi1 = 0;
    int   code = n0 + quad * 4;              // this lane's reg-0 code of tile 0

    for (int tile = 0; tile < CHUNK / 16; tile++) {
        L8 ahu, alu;
        ahu.u = *(const uint4*)(abase + (size_t)tile * 2048);
        alu.u = *(const uint4*)(abase + (size_t)tile * 2048 + 64);
        const half8 ah = ahu.h, al = alu.h;

        f32x4 acc0 = {0.f, 0.f, 0.f, 0.f};
        f32x4 acc1 = {0.f, 0.f, 0.f, 0.f};
        acc0 = __builtin_amdgcn_mfma_f32_16x16x32_f16(ah, b0h, acc0, 0, 0, 0);
        acc1 = __builtin_amdgcn_mfma_f32_16x16x32_f16(ah, b1h, acc1, 0, 0, 0);
        acc0 = __builtin_amdgcn_mfma_f32_16x16x32_f16(ah, b0l, acc0, 0, 0, 0);
        acc1 = __builtin_amdgcn_mfma_f32_16x16x32_f16(ah, b1l, acc1, 0, 0, 0);
        acc0 = __builtin_amdgcn_mfma_f32_16x16x32_f16(al, b0h, acc0, 0, 0, 0);
        acc1 = __builtin_amdgcn_mfma_f32_16x16x32_f16(al, b1h, acc1, 0, 0, 0);
        acc0 = __builtin_amdgcn_mfma_f32_16x16x32_f16(al, b0l, acc0, 0, 0, 0);
        acc1 = __builtin_amdgcn_mfma_f32_16x16x32_f16(al, b1l, acc1, 0, 0, 0);

#pragma unroll
        for (int r = 0; r < 4; r++) {
            const float v0 = acc0[r];
            if (v0 > best0) { best0 = v0; bi0 = code + r; }
            const float v1 = acc1[r];
            if (v1 > best1) { best1 = v1; bi1 = code + r; }
        }
        code += 16;
    }

    // reduce across the 4 quads holding the same position (xor 16, 32)
#pragma unroll
    for (int off = 16; off < 64; off <<= 1) {
        const float ov0 = __shfl_xor(best0, off);
        const int   oi0 = __shfl_xor(bi0, off);
        if (ov0 > best0 || (ov0 == best0 && oi0 < bi0)) { best0 = ov0; bi0 = oi0; }
        const float ov1 = __shfl_xor(best1, off);
        const int   oi1 = __shfl_xor(bi1, off);
        if (ov1 > best1 || (ov1 == best1 && oi1 < bi1)) { best1 = ov1; bi1 = oi1; }
    }
    if (quad == 0) {
        pval[(size_t)chunk * P_TOTAL + wp0 + col]      = best0;
        pidx[(size_t)chunk * P_TOTAL + wp0 + col]      = bi0;
        pval[(size_t)chunk * P_TOTAL + wp0 + 16 + col] = best1;
        pidx[(size_t)chunk * P_TOTAL + wp0 + 16 + col] = bi1;
    }
}

// ---------------------------------------------------------------------------
// Kernel D: combine chunk partials (ascending k keeps lowest index on ties),
// histogram via atomics, quantization-loss partial sum.
// ---------------------------------------------------------------------------
__global__ __launch_bounds__(256) void combine_kernel(
    const float* __restrict__ pval, const int* __restrict__ pidx,
    const float* __restrict__ z, const float* __restrict__ invz,
    const float* __restrict__ en,
    int* __restrict__ idx, int* __restrict__ hist, float* __restrict__ lossAcc)
{
    const int p = blockIdx.x * 256 + threadIdx.x;
    float best = -3e38f;
    int   bi   = 0;
#pragma unroll
    for (int k = 0; k < NCHUNK; k++) {
        const float v = pval[k * P_TOTAL + p];
        const int   i = pidx[k * P_TOTAL + p];
        if (v > best) { best = v; bi = i; }
    }
    idx[p] = bi;
    atomicAdd(&hist[bi], 1);

    const float iv = invz[p];
    const float4* zsrc = reinterpret_cast<const float4*>(z + (size_t)p * DD);
    const float4* esrc = reinterpret_cast<const float4*>(en + (size_t)bi * DD);
    float ls = 0.f;
#pragma unroll
    for (int q = 0; q < 8; q++) {
        const float4 zv = zsrc[q];
        const float4 ev = esrc[q];
        const float dx = zv.x * iv - ev.x;
        const float dy = zv.y * iv - ev.y;
        const float dz = zv.z * iv - ev.z;
        const float dw = zv.w * iv - ev.w;
        ls += dx * dx + dy * dy + dz * dz + dw * dw;
    }
    __shared__ float red[256];
    red[threadIdx.x] = ls;
    __syncthreads();
    for (int s = 128; s > 0; s >>= 1) {
        if (threadIdx.x < s) red[threadIdx.x] += red[threadIdx.x + s];
        __syncthreads();
    }
    if (threadIdx.x == 0) atomicAdd(lossAcc, red[0]);
}

// ---------------------------------------------------------------------------
// Kernel E: out[b][c][hw] = sum_d en[idx[p]][d] * exp_w[c][d] + exp_b[c]
// Grid 512 = 256 position-groups x 2 c-halves. latents in LDS (pad 33),
// exp_w wave-uniform s_load, stores coalesced along hw.
// ---------------------------------------------------------------------------
__global__ __launch_bounds__(256) void expand_kernel(
    const int* __restrict__ idx, const float* __restrict__ en,
    const float* __restrict__ ew, const float* __restrict__ eb,
    float* __restrict__ out)
{
    const int t     = threadIdx.x;
    const int chalf = blockIdx.x & 1;
    const int pg    = blockIdx.x >> 1;
    const int p0    = pg * 64;
    const int b     = p0 >> 10;
    const int hw0   = p0 & 1023;

    __shared__ float lat[64 * 33];
    for (int i = t; i < 64 * DD; i += 256) {
        const int pl = i >> 5, d = i & 31;
        lat[pl * 33 + d] = en[(size_t)idx[p0 + pl] * DD + d];
    }
    __syncthreads();

    const int hw_l = t & 63;
    const int cg   = t >> 6;        // wave-uniform
    float lr[32];
#pragma unroll
    for (int d = 0; d < DD; d++) lr[d] = lat[hw_l * 33 + d];

    float* outb = out + (size_t)b * (CCH * HWSZ) + hw0 + hw_l;
    const int c0 = chalf * 256 + cg * 64;
#pragma unroll 4
    for (int k = 0; k < 64; k++) {
        const int c = c0 + k;
        const float* ewc = ew + (size_t)c * DD;      // wave-uniform -> SGPRs
        float s0 = 0.f, s1 = 0.f, s2 = 0.f, s3 = 0.f;
#pragma unroll
        for (int d = 0; d < DD; d += 4) {
            s0 = fmaf(lr[d + 0], ewc[d + 0], s0);
            s1 = fmaf(lr[d + 1], ewc[d + 1], s1);
            s2 = fmaf(lr[d + 2], ewc[d + 2], s2);
            s3 = fmaf(lr[d + 3], ewc[d + 3], s3);
        }
        outb[(size_t)c * HWSZ] = (s0 + s1) + (s2 + s3) + eb[c];
    }
}

// ---------------------------------------------------------------------------
// Kernel F: perplexity from histogram + finalize loss scalar.
// ---------------------------------------------------------------------------
__global__ __launch_bounds__(256) void final_kernel(
    const int* __restrict__ hist, const float* __restrict__ lossAcc,
    float* __restrict__ out_scalars)
{
    __shared__ float red[256];
    float h = 0.f;
    for (int i = threadIdx.x; i < NCODES; i += 256) {
        const float u = (float)hist[i] * (1.f / (float)P_TOTAL);
        h -= u * logf(u + 1e-6f);
    }
    red[threadIdx.x] = h;
    __syncthreads();
    for (int s = 128; s > 0; s >>= 1) {
        if (threadIdx.x < s) red[threadIdx.x] += red[threadIdx.x + s];
        __syncthreads();
    }
    if (threadIdx.x == 0) {
        out_scalars[0] = lossAcc[0] * (1.f / (float)(P_TOTAL * DD));  // mean
        out_scalars[1] = expf(red[0]);
    }
}

// ---------------------------------------------------------------------------
// Workspace layout (bytes):
//   z      @ 0        : 16384*32*4  = 2,097,152
//   invz   @ 2097152  : 16384*4     =    65,536
//   en     @ 2162688  : 16384*32*4  = 2,097,152
//   zf16   @ 4259840  : 16384*128   = 2,097,152  (hi|lo f16 rows, x4096)
//   ef16   @ 6356992  : 16384*128   = 2,097,152
//   pval   @ 8454144  : 16*16384*4  = 1,048,576
//   pidx   @ 9502720  : 16*16384*4  = 1,048,576
//   idx    @ 10551296 : 16384*4     =    65,536
//   hist   @ 10616832 : 16384*4     =    65,536
//   loss   @ 10682368 : 4                         (total ~10.7 MB)
// ---------------------------------------------------------------------------
extern "C" void kernel_launch(void* const* d_in, const int* in_sizes, int n_in,
                              void* d_out, int out_size, void* d_ws, size_t ws_size,
                              hipStream_t stream)
{
    const float* enc = (const float*)d_in[0];   // [16,512,32,32]
    const float* emb = (const float*)d_in[1];   // [16384,32]
    const float* pw  = (const float*)d_in[2];   // [32,512]
    const float* pb  = (const float*)d_in[3];   // [32]
    const float* ew  = (const float*)d_in[4];   // [512,32]
    const float* eb  = (const float*)d_in[5];   // [512]
    float* out = (float*)d_out;                 // 8388608 + loss + perplexity

    char* ws = (char*)d_ws;
    float* z       = (float*)(ws + 0);
    float* invz    = (float*)(ws + 2097152);
    float* en      = (float*)(ws + 2162688);
    char*  zf16    = ws + 4259840;
    char*  ef16    = ws + 6356992;
    float* pval    = (float*)(ws + 8454144);
    int*   pidx    = (int*)  (ws + 9502720);
    int*   idx     = (int*)  (ws + 10551296);
    int*   hist    = (int*)  (ws + 10616832);
    float* lossAcc = (float*)(ws + 10682368);

    // hist + lossAcc are contiguous: zero both in one async memset.
    hipMemsetAsync(hist, 0, NCODES * 4 + 4, stream);

    proj_kernel   <<<P_TOTAL / 64, 256, 0, stream>>>(enc, pw, pb, z, invz, zf16);
    enorm_kernel  <<<NCODES / 256, 256, 0, stream>>>(emb, en, ef16);
    argmax_kernel <<<128 * NCHUNK, 256, 0, stream>>>(zf16, ef16, pval, pidx);
    combine_kernel<<<P_TOTAL / 256, 256, 0, stream>>>(pval, pidx, z, invz, en,
                                                      idx, hist, lossAcc);
    expand_kernel <<<512, 256, 0, stream>>>(idx, en, ew, eb, out);
    final_kernel  <<<1, 256, 0, stream>>>(hist, lossAcc, out + 8388608);
}

// Round 5
// 341.776 us; speedup vs baseline: 1.7766x; 1.0613x over previous
//
#include <hip/hip_runtime.h>
#include <cstdint>

// Problem constants (from reference setup_inputs)
#define BATCH   16
#define CCH     512
#define DD      32
#define NCODES  16384
#define HWSZ    1024            // 32*32
#define P_TOTAL 16384           // BATCH * HWSZ
#define NCHUNK  16
#define CHUNK   (NCODES / NCHUNK)   // 1024 codes per chunk

typedef _Float16 half8 __attribute__((ext_vector_type(8)));
typedef float    f32x4 __attribute__((ext_vector_type(4)));

union H8 { _Float16 h[8]; uint4 u; };
union L8 { uint4 u; half8 h; };

// f16 split row layout: row = 128 B = [32 f16 hi | 32 f16 lo], values scaled
// by 2^12 so lo-terms stay in f16 normal range (|z|<6 -> hi<24576<65504).
// sim accumulates at scale 2^24; argmax is scale-invariant.

// ---------------------------------------------------------------------------
// Kernel A: z[p][d] = sum_c enc[b][c][hw] * proj_w[d][c] + proj_b[d]
// block: 256 thr = 64 positions x 4 d-groups of 8; 16 loads in flight/wave.
// dg forced wave-uniform via readfirstlane -> pw loads become s_load_dwordx16
// (R3 bug: t>>6 unprovable-uniform -> thousands of vector loads).
// Epilogue: z fp32, invz, and zf16 split rows (hi|lo, scaled 2^12).
// ---------------------------------------------------------------------------
__global__ __launch_bounds__(256) void proj_kernel(
    const float* __restrict__ enc, const float* __restrict__ pw,
    const float* __restrict__ pb, float* __restrict__ z,
    float* __restrict__ invz, char* __restrict__ zf16)
{
    const int t    = threadIdx.x;
    const int hw_l = t & 63;
    const int dg   = __builtin_amdgcn_readfirstlane(t >> 6);   // SGPR-uniform
    const int p0   = blockIdx.x * 64;
    const int b    = p0 >> 10;
    const int hw   = (p0 & 1023) + hw_l;
    const float* encb = enc + (size_t)b * (CCH * HWSZ) + hw;

    float acc[8];
#pragma unroll
    for (int j = 0; j < 8; j++) acc[j] = 0.f;

    for (int c0 = 0; c0 < CCH; c0 += 16) {
        float ev[16];
#pragma unroll
        for (int u = 0; u < 16; u++)                 // 16 loads in flight
            ev[u] = encb[(size_t)(c0 + u) * HWSZ];
#pragma unroll
        for (int u = 0; u < 16; u++)
#pragma unroll
            for (int j = 0; j < 8; j++)              // uniform -> s_load
                acc[j] = fmaf(ev[u], pw[(dg * 8 + j) * CCH + c0 + u], acc[j]);
    }

    const int p = p0 + hw_l;
    float ssq = 0.f;
    H8 hi, lo;
#pragma unroll
    for (int j = 0; j < 8; j++) {
        const float v = acc[j] + pb[dg * 8 + j];
        z[(size_t)p * DD + dg * 8 + j] = v;
        ssq = fmaf(v, v, ssq);
        const float vs = v * 4096.f;
        const _Float16 h = (_Float16)vs;
        hi.h[j] = h;
        lo.h[j] = (_Float16)(vs - (float)h);
    }
    char* row = zf16 + (size_t)p * 128;
    *(uint4*)(row + dg * 16)      = hi.u;
    *(uint4*)(row + 64 + dg * 16) = lo.u;

    __shared__ float red[4][64];
    red[dg][hw_l] = ssq;
    __syncthreads();
    if (t < 64) {
        const float tot = red[0][t] + red[1][t] + red[2][t] + red[3][t];
        invz[p0 + t] = 1.f / fmaxf(sqrtf(tot), 1e-6f);
    }
}

// ---------------------------------------------------------------------------
// Kernel B: en[r] = emb[r]/max(||emb[r]||,eps) fp32 + ef16 split rows.
// 256 blocks x 64 thr (R3 ran 64 blocks -> 3/4 of GPU idle).
// ---------------------------------------------------------------------------
__global__ __launch_bounds__(64) void enorm_kernel(
    const float* __restrict__ e, float* __restrict__ en,
    char* __restrict__ ef16)
{
    const int r = blockIdx.x * 64 + threadIdx.x;
    const float4* src = reinterpret_cast<const float4*>(e + (size_t)r * DD);
    float4 v[8];
    float ssq = 0.f;
#pragma unroll
    for (int q = 0; q < 8; q++) {
        v[q] = src[q];
        ssq += v[q].x * v[q].x + v[q].y * v[q].y + v[q].z * v[q].z + v[q].w * v[q].w;
    }
    const float inv = 1.f / fmaxf(sqrtf(ssq), 1e-6f);
    float4* dst = reinterpret_cast<float4*>(en + (size_t)r * DD);
    char* row = ef16 + (size_t)r * 128;
#pragma unroll
    for (int q = 0; q < 8; q += 2) {                 // 8 values per iter
        H8 hi, lo;
#pragma unroll
        for (int u = 0; u < 2; u++) {
            float4 o;
            o.x = v[q + u].x * inv; o.y = v[q + u].y * inv;
            o.z = v[q + u].z * inv; o.w = v[q + u].w * inv;
            dst[q + u] = o;
            const float s[4] = {o.x * 4096.f, o.y * 4096.f, o.z * 4096.f, o.w * 4096.f};
#pragma unroll
            for (int j = 0; j < 4; j++) {
                const _Float16 h = (_Float16)s[j];
                hi.h[u * 4 + j] = h;
                lo.h[u * 4 + j] = (_Float16)(s[j] - (float)h);
            }
        }
        *(uint4*)(row + q * 8)      = hi.u;          // hi block: bytes [0,64)
        *(uint4*)(row + 64 + q * 8) = lo.u;          // lo block: bytes [64,128)
    }
}

// ---------------------------------------------------------------------------
// Kernel C: fused MFMA sims + argmax over one 1024-code chunk.
// R4: one-tile-ahead register prefetch of the A (code) fragments + the 8
// MFMAs restructured into 4 independent depth-2 chains (t0 = hh+ll,
// t1 = hl+lh per pos-tile; summed in f32 epilogue) — R3 had 2 serial
// depth-4 chains + unprefetched L2 loads -> latency-bound (46% pipe busy).
// D layout: code=(lane>>4)*4+reg, pos=lane&15 -> argmax reg-local, then
// shfl_xor(16,32) with equal->lower-idx tie-break (numpy first-occurrence).
// ---------------------------------------------------------------------------
__global__ __launch_bounds__(256) void argmax_kernel(
    const char* __restrict__ zf16, const char* __restrict__ ef16,
    float* __restrict__ pval, int* __restrict__ pidx)
{
    const int w    = threadIdx.x >> 6;       // wave 0..3
    const int lane = threadIdx.x & 63;
    const int col  = lane & 15;
    const int quad = lane >> 4;
    const int pg    = blockIdx.x & 127;      // 128 position groups of 128
    const int chunk = blockIdx.x >> 7;       // 16 chunks of 1024 codes
    const int wp0   = pg * 128 + w * 32;     // wave position base

    // B fragments (z): pos-tile0 rows wp0+col, pos-tile1 rows wp0+16+col
    half8 b0h, b0l, b1h, b1l;
    {
        const char* r0 = zf16 + (size_t)(wp0 + col) * 128 + quad * 16;
        const char* r1 = r0 + 16 * 128;
        L8 a; a.u = *(const uint4*)(r0);       b0h = a.h;
        L8 b; b.u = *(const uint4*)(r0 + 64);  b0l = b.h;
        L8 c; c.u = *(const uint4*)(r1);       b1h = c.h;
        L8 d; d.u = *(const uint4*)(r1 + 64);  b1l = d.h;
    }

    const int n0 = chunk * CHUNK;
    const char* abase = ef16 + (size_t)(n0 + col) * 128 + quad * 16;

    float best0 = -3e38f, best1 = -3e38f;
    int   bi0 = 0, bi1 = 0;
    int   code = n0 + quad * 4;              // this lane's reg-0 code of tile 0

    // prime the prefetch pipeline
    uint4 pa_h = *(const uint4*)(abase);
    uint4 pa_l = *(const uint4*)(abase + 64);

    for (int tile = 0; tile < CHUNK / 16; tile++) {
        L8 ahu, alu;
        ahu.u = pa_h;
        alu.u = pa_l;
        // prefetch next tile (last iter over-reads ~2KB into pval region: safe)
        const char* nxt = abase + (size_t)(tile + 1) * 2048;
        pa_h = *(const uint4*)(nxt);
        pa_l = *(const uint4*)(nxt + 64);

        const half8 ah = ahu.h, al = alu.h;

        // 4 independent depth-2 MFMA chains
        f32x4 t00 = {0.f, 0.f, 0.f, 0.f}, t01 = {0.f, 0.f, 0.f, 0.f};
        f32x4 t10 = {0.f, 0.f, 0.f, 0.f}, t11 = {0.f, 0.f, 0.f, 0.f};
        t00 = __builtin_amdgcn_mfma_f32_16x16x32_f16(ah, b0h, t00, 0, 0, 0); // hh
        t01 = __builtin_amdgcn_mfma_f32_16x16x32_f16(ah, b0l, t01, 0, 0, 0); // hl
        t10 = __builtin_amdgcn_mfma_f32_16x16x32_f16(ah, b1h, t10, 0, 0, 0);
        t11 = __builtin_amdgcn_mfma_f32_16x16x32_f16(ah, b1l, t11, 0, 0, 0);
        t00 = __builtin_amdgcn_mfma_f32_16x16x32_f16(al, b0l, t00, 0, 0, 0); // ll
        t01 = __builtin_amdgcn_mfma_f32_16x16x32_f16(al, b0h, t01, 0, 0, 0); // lh
        t10 = __builtin_amdgcn_mfma_f32_16x16x32_f16(al, b1l, t10, 0, 0, 0);
        t11 = __builtin_amdgcn_mfma_f32_16x16x32_f16(al, b1h, t11, 0, 0, 0);

#pragma unroll
        for (int r = 0; r < 4; r++) {
            const float v0 = t00[r] + t01[r];
            if (v0 > best0) { best0 = v0; bi0 = code + r; }
            const float v1 = t10[r] + t11[r];
            if (v1 > best1) { best1 = v1; bi1 = code + r; }
        }
        code += 16;
    }

    // reduce across the 4 quads holding the same position (xor 16, 32)
#pragma unroll
    for (int off = 16; off < 64; off <<= 1) {
        const float ov0 = __shfl_xor(best0, off);
        const int   oi0 = __shfl_xor(bi0, off);
        if (ov0 > best0 || (ov0 == best0 && oi0 < bi0)) { best0 = ov0; bi0 = oi0; }
        const float ov1 = __shfl_xor(best1, off);
        const int   oi1 = __shfl_xor(bi1, off);
        if (ov1 > best1 || (ov1 == best1 && oi1 < bi1)) { best1 = ov1; bi1 = oi1; }
    }
    if (quad == 0) {
        pval[(size_t)chunk * P_TOTAL + wp0 + col]      = best0;
        pidx[(size_t)chunk * P_TOTAL + wp0 + col]      = bi0;
        pval[(size_t)chunk * P_TOTAL + wp0 + 16 + col] = best1;
        pidx[(size_t)chunk * P_TOTAL + wp0 + 16 + col] = bi1;
    }
}

// ---------------------------------------------------------------------------
// Kernel D: combine chunk partials (ascending k keeps lowest index on ties),
// histogram via atomics, quantization-loss partial sum.
// 256 blocks x 64 thr (R3 ran 64 blocks -> 3/4 of GPU idle).
// ---------------------------------------------------------------------------
__global__ __launch_bounds__(64) void combine_kernel(
    const float* __restrict__ pval, const int* __restrict__ pidx,
    const float* __restrict__ z, const float* __restrict__ invz,
    const float* __restrict__ en,
    int* __restrict__ idx, int* __restrict__ hist, float* __restrict__ lossAcc)
{
    const int p = blockIdx.x * 64 + threadIdx.x;
    float best = -3e38f;
    int   bi   = 0;
#pragma unroll
    for (int k = 0; k < NCHUNK; k++) {
        const float v = pval[k * P_TOTAL + p];
        const int   i = pidx[k * P_TOTAL + p];
        if (v > best) { best = v; bi = i; }
    }
    idx[p] = bi;
    atomicAdd(&hist[bi], 1);

    const float iv = invz[p];
    const float4* zsrc = reinterpret_cast<const float4*>(z + (size_t)p * DD);
    const float4* esrc = reinterpret_cast<const float4*>(en + (size_t)bi * DD);
    float ls = 0.f;
#pragma unroll
    for (int q = 0; q < 8; q++) {
        const float4 zv = zsrc[q];
        const float4 ev = esrc[q];
        const float dx = zv.x * iv - ev.x;
        const float dy = zv.y * iv - ev.y;
        const float dz = zv.z * iv - ev.z;
        const float dw = zv.w * iv - ev.w;
        ls += dx * dx + dy * dy + dz * dz + dw * dw;
    }
    __shared__ float red[64];
    red[threadIdx.x] = ls;
    __syncthreads();
    for (int s = 32; s > 0; s >>= 1) {
        if (threadIdx.x < s) red[threadIdx.x] += red[threadIdx.x + s];
        __syncthreads();
    }
    if (threadIdx.x == 0) atomicAdd(lossAcc, red[0]);
}

// ---------------------------------------------------------------------------
// Kernel E: out[b][c][hw] = sum_d en[idx[p]][d] * exp_w[c][d] + exp_b[c]
// Grid 512 = 256 position-groups x 2 c-halves. cg forced wave-uniform via
// readfirstlane -> ew loads become s_load_dwordx16 (same R3 bug as proj).
// latents in LDS (pad 33), stores coalesced along hw.
// ---------------------------------------------------------------------------
__global__ __launch_bounds__(256) void expand_kernel(
    const int* __restrict__ idx, const float* __restrict__ en,
    const float* __restrict__ ew, const float* __restrict__ eb,
    float* __restrict__ out)
{
    const int t     = threadIdx.x;
    const int chalf = blockIdx.x & 1;
    const int pg    = blockIdx.x >> 1;
    const int p0    = pg * 64;
    const int b     = p0 >> 10;
    const int hw0   = p0 & 1023;

    __shared__ float lat[64 * 33];
    for (int i = t; i < 64 * DD; i += 256) {
        const int pl = i >> 5, d = i & 31;
        lat[pl * 33 + d] = en[(size_t)idx[p0 + pl] * DD + d];
    }
    __syncthreads();

    const int hw_l = t & 63;
    const int cg   = __builtin_amdgcn_readfirstlane(t >> 6);   // SGPR-uniform
    float lr[32];
#pragma unroll
    for (int d = 0; d < DD; d++) lr[d] = lat[hw_l * 33 + d];

    float* outb = out + (size_t)b * (CCH * HWSZ) + hw0 + hw_l;
    const int c0 = chalf * 256 + cg * 64;
#pragma unroll 4
    for (int k = 0; k < 64; k++) {
        const int c = c0 + k;
        const float* ewc = ew + (size_t)c * DD;      // uniform -> s_load
        float s0 = 0.f, s1 = 0.f, s2 = 0.f, s3 = 0.f;
#pragma unroll
        for (int d = 0; d < DD; d += 4) {
            s0 = fmaf(lr[d + 0], ewc[d + 0], s0);
            s1 = fmaf(lr[d + 1], ewc[d + 1], s1);
            s2 = fmaf(lr[d + 2], ewc[d + 2], s2);
            s3 = fmaf(lr[d + 3], ewc[d + 3], s3);
        }
        outb[(size_t)c * HWSZ] = (s0 + s1) + (s2 + s3) + eb[c];
    }
}

// ---------------------------------------------------------------------------
// Kernel F: perplexity from histogram + finalize loss scalar.
// ---------------------------------------------------------------------------
__global__ __launch_bounds__(256) void final_kernel(
    const int* __restrict__ hist, const float* __restrict__ lossAcc,
    float* __restrict__ out_scalars)
{
    __shared__ float red[256];
    float h = 0.f;
    for (int i = threadIdx.x; i < NCODES; i += 256) {
        const float u = (float)hist[i] * (1.f / (float)P_TOTAL);
        h -= u * logf(u + 1e-6f);
    }
    red[threadIdx.x] = h;
    __syncthreads();
    for (int s = 128; s > 0; s >>= 1) {
        if (threadIdx.x < s) red[threadIdx.x] += red[threadIdx.x + s];
        __syncthreads();
    }
    if (threadIdx.x == 0) {
        out_scalars[0] = lossAcc[0] * (1.f / (float)(P_TOTAL * DD));  // mean
        out_scalars[1] = expf(red[0]);
    }
}

// ---------------------------------------------------------------------------
// Workspace layout (bytes):
//   z      @ 0        : 16384*32*4  = 2,097,152
//   invz   @ 2097152  : 16384*4     =    65,536
//   en     @ 2162688  : 16384*32*4  = 2,097,152
//   zf16   @ 4259840  : 16384*128   = 2,097,152  (hi|lo f16 rows, x4096)
//   ef16   @ 6356992  : 16384*128   = 2,097,152
//   pval   @ 8454144  : 16*16384*4  = 1,048,576
//   pidx   @ 9502720  : 16*16384*4  = 1,048,576
//   idx    @ 10551296 : 16384*4     =    65,536
//   hist   @ 10616832 : 16384*4     =    65,536
//   loss   @ 10682368 : 4                         (total ~10.7 MB)
// ---------------------------------------------------------------------------
extern "C" void kernel_launch(void* const* d_in, const int* in_sizes, int n_in,
                              void* d_out, int out_size, void* d_ws, size_t ws_size,
                              hipStream_t stream)
{
    const float* enc = (const float*)d_in[0];   // [16,512,32,32]
    const float* emb = (const float*)d_in[1];   // [16384,32]
    const float* pw  = (const float*)d_in[2];   // [32,512]
    const float* pb  = (const float*)d_in[3];   // [32]
    const float* ew  = (const float*)d_in[4];   // [512,32]
    const float* eb  = (const float*)d_in[5];   // [512]
    float* out = (float*)d_out;                 // 8388608 + loss + perplexity

    char* ws = (char*)d_ws;
    float* z       = (float*)(ws + 0);
    float* invz    = (float*)(ws + 2097152);
    float* en      = (float*)(ws + 2162688);
    char*  zf16    = ws + 4259840;
    char*  ef16    = ws + 6356992;
    float* pval    = (float*)(ws + 8454144);
    int*   pidx    = (int*)  (ws + 9502720);
    int*   idx     = (int*)  (ws + 10551296);
    int*   hist    = (int*)  (ws + 10616832);
    float* lossAcc = (float*)(ws + 10682368);

    // hist + lossAcc are contiguous: zero both in one async memset.
    hipMemsetAsync(hist, 0, NCODES * 4 + 4, stream);

    proj_kernel   <<<P_TOTAL / 64, 256, 0, stream>>>(enc, pw, pb, z, invz, zf16);
    enorm_kernel  <<<NCODES / 64, 64, 0, stream>>>(emb, en, ef16);
    argmax_kernel <<<128 * NCHUNK, 256, 0, stream>>>(zf16, ef16, pval, pidx);
    combine_kernel<<<P_TOTAL / 64, 64, 0, stream>>>(pval, pidx, z, invz, en,
                                                    idx, hist, lossAcc);
    expand_kernel <<<512, 256, 0, stream>>>(idx, en, ew, eb, out);
    final_kernel  <<<1, 256, 0, stream>>>(hist, lossAcc, out + 8388608);
}

// Round 6
// 252.475 us; speedup vs baseline: 2.4049x; 1.3537x over previous
//
#include <hip/hip_runtime.h>
#include <cstdint>

// Problem constants (from reference setup_inputs)
#define BATCH   16
#define CCH     512
#define DD      32
#define NCODES  16384
#define HWSZ    1024            // 32*32
#define P_TOTAL 16384           // BATCH * HWSZ
#define NCHUNK  16
#define CHUNK   (NCODES / NCHUNK)   // 1024 codes per chunk

typedef _Float16 half8 __attribute__((ext_vector_type(8)));
typedef float    f32x4 __attribute__((ext_vector_type(4)));

union H8 { _Float16 h[8]; uint4 u; };
union L8 { uint4 u; half8 h; };

// f16 split row layout: row = 128 B = [32 f16 hi | 32 f16 lo], values scaled
// by 2^12 so lo-terms stay in f16 normal range (|z|<6 -> hi<24576<65504).
// sim accumulates at scale 2^24; argmax is scale-invariant.

// ---------------------------------------------------------------------------
// Kernel PREP (fused): grid 384 blocks x 256 thr.
//   blocks [0,256):  proj  z[p][d] = sum_c enc*pw + pb, invz, zf16 split rows
//   blocks [256,320): enorm en rows + ef16 split rows
//   blocks [320,384): zero hist (+ lossAcc/entAcc) — replaces hipMemsetAsync
// ---------------------------------------------------------------------------
__global__ __launch_bounds__(256) void prep_kernel(
    const float* __restrict__ enc, const float* __restrict__ pw,
    const float* __restrict__ pb, const float* __restrict__ emb,
    float* __restrict__ z, float* __restrict__ invz, char* __restrict__ zf16,
    float* __restrict__ en, char* __restrict__ ef16,
    int* __restrict__ hist, float* __restrict__ scalarAcc)
{
    const int t = threadIdx.x;

    if (blockIdx.x >= 320) {                 // ---- hist/scalar zeroing ----
        const int i = (blockIdx.x - 320) * 256 + t;
        hist[i] = 0;
        if (blockIdx.x == 320 && t < 2) scalarAcc[t] = 0.f;   // loss, entropy
        return;
    }

    if (blockIdx.x >= 256) {                 // ---- enorm ----
        const int r = (blockIdx.x - 256) * 256 + t;
        const float4* src = reinterpret_cast<const float4*>(emb + (size_t)r * DD);
        float4 v[8];
        float ssq = 0.f;
#pragma unroll
        for (int q = 0; q < 8; q++) {
            v[q] = src[q];
            ssq += v[q].x * v[q].x + v[q].y * v[q].y + v[q].z * v[q].z + v[q].w * v[q].w;
        }
        const float inv = 1.f / fmaxf(sqrtf(ssq), 1e-6f);
        float4* dst = reinterpret_cast<float4*>(en + (size_t)r * DD);
        char* row = ef16 + (size_t)r * 128;
#pragma unroll
        for (int q = 0; q < 8; q += 2) {
            H8 hi, lo;
#pragma unroll
            for (int u = 0; u < 2; u++) {
                float4 o;
                o.x = v[q + u].x * inv; o.y = v[q + u].y * inv;
                o.z = v[q + u].z * inv; o.w = v[q + u].w * inv;
                dst[q + u] = o;
                const float s[4] = {o.x * 4096.f, o.y * 4096.f, o.z * 4096.f, o.w * 4096.f};
#pragma unroll
                for (int j = 0; j < 4; j++) {
                    const _Float16 h = (_Float16)s[j];
                    hi.h[u * 4 + j] = h;
                    lo.h[u * 4 + j] = (_Float16)(s[j] - (float)h);
                }
            }
            *(uint4*)(row + q * 8)      = hi.u;
            *(uint4*)(row + 64 + q * 8) = lo.u;
        }
        return;
    }

    // ---- proj ----
    const int hw_l = t & 63;
    const int dg   = __builtin_amdgcn_readfirstlane(t >> 6);   // SGPR-uniform
    const int p0   = blockIdx.x * 64;
    const int b    = p0 >> 10;
    const int hw   = (p0 & 1023) + hw_l;
    const float* encb = enc + (size_t)b * (CCH * HWSZ) + hw;

    float acc[8];
#pragma unroll
    for (int j = 0; j < 8; j++) acc[j] = 0.f;

    for (int c0 = 0; c0 < CCH; c0 += 16) {
        float ev[16];
#pragma unroll
        for (int u = 0; u < 16; u++)                 // 16 loads in flight
            ev[u] = encb[(size_t)(c0 + u) * HWSZ];
#pragma unroll
        for (int u = 0; u < 16; u++)
#pragma unroll
            for (int j = 0; j < 8; j++)              // uniform -> s_load
                acc[j] = fmaf(ev[u], pw[(dg * 8 + j) * CCH + c0 + u], acc[j]);
    }

    const int p = p0 + hw_l;
    float ssq = 0.f;
    H8 hi, lo;
#pragma unroll
    for (int j = 0; j < 8; j++) {
        const float v = acc[j] + pb[dg * 8 + j];
        z[(size_t)p * DD + dg * 8 + j] = v;
        ssq = fmaf(v, v, ssq);
        const float vs = v * 4096.f;
        const _Float16 h = (_Float16)vs;
        hi.h[j] = h;
        lo.h[j] = (_Float16)(vs - (float)h);
    }
    char* row = zf16 + (size_t)p * 128;
    *(uint4*)(row + dg * 16)      = hi.u;
    *(uint4*)(row + 64 + dg * 16) = lo.u;

    __shared__ float red[4][64];
    red[dg][hw_l] = ssq;
    __syncthreads();
    if (t < 64) {
        const float tot = red[0][t] + red[1][t] + red[2][t] + red[3][t];
        invz[p0 + t] = 1.f / fmaxf(sqrtf(tot), 1e-6f);
    }
}

// ---------------------------------------------------------------------------
// Kernel C: fused MFMA sims + argmax over one 1024-code chunk.
// R5: 64 positions/wave (4 B-frag pairs) -> each A-tile load feeds 16 MFMAs;
// hi/lo cross-terms folded into ONE depth-4 chain per pos-tile via the MFMA
// C operand (kills the f32 adds); 4 independent chains interleaved.
// D layout: code=(lane>>4)*4+reg, pos=lane&15 -> argmax reg-local, then
// shfl_xor(16,32) with equal->lower-idx tie-break (numpy first-occurrence).
// ---------------------------------------------------------------------------
__global__ __launch_bounds__(256) void argmax_kernel(
    const char* __restrict__ zf16, const char* __restrict__ ef16,
    float* __restrict__ pval, int* __restrict__ pidx)
{
    const int w    = threadIdx.x >> 6;       // wave 0..3
    const int lane = threadIdx.x & 63;
    const int col  = lane & 15;
    const int quad = lane >> 4;
    const int pg    = blockIdx.x & 63;       // 64 position groups of 256
    const int chunk = blockIdx.x >> 6;       // 16 chunks of 1024 codes
    const int wp0   = pg * 256 + w * 64;     // wave position base (64 pos)

    // B fragments (z): pos-tile tt rows wp0 + tt*16 + col
    half8 bh[4], bl[4];
#pragma unroll
    for (int tt = 0; tt < 4; tt++) {
        const char* r = zf16 + (size_t)(wp0 + tt * 16 + col) * 128 + quad * 16;
        L8 a; a.u = *(const uint4*)(r);       bh[tt] = a.h;
        L8 b; b.u = *(const uint4*)(r + 64);  bl[tt] = b.h;
    }

    const int n0 = chunk * CHUNK;
    const char* abase = ef16 + (size_t)(n0 + col) * 128 + quad * 16;

    float best[4] = {-3e38f, -3e38f, -3e38f, -3e38f};
    int   bidx[4] = {0, 0, 0, 0};
    int   code = n0 + quad * 4;              // this lane's reg-0 code of tile 0

    // prime the prefetch pipeline
    uint4 pa_h = *(const uint4*)(abase);
    uint4 pa_l = *(const uint4*)(abase + 64);
    const f32x4 zero4 = {0.f, 0.f, 0.f, 0.f};

    for (int tile = 0; tile < CHUNK / 16; tile++) {
        L8 ahu, alu;
        ahu.u = pa_h;
        alu.u = pa_l;
        // prefetch next tile (last iter over-reads ~2KB into pval region: safe)
        const char* nxt = abase + (size_t)(tile + 1) * 2048;
        pa_h = *(const uint4*)(nxt);
        pa_l = *(const uint4*)(nxt + 64);

        const half8 ah = ahu.h, al = alu.h;

        // 4 independent depth-4 chains (hh -> hl -> lh -> ll via C operand)
        f32x4 acc[4];
#pragma unroll
        for (int tt = 0; tt < 4; tt++)
            acc[tt] = __builtin_amdgcn_mfma_f32_16x16x32_f16(ah, bh[tt], zero4, 0, 0, 0);
#pragma unroll
        for (int tt = 0; tt < 4; tt++)
            acc[tt] = __builtin_amdgcn_mfma_f32_16x16x32_f16(ah, bl[tt], acc[tt], 0, 0, 0);
#pragma unroll
        for (int tt = 0; tt < 4; tt++)
            acc[tt] = __builtin_amdgcn_mfma_f32_16x16x32_f16(al, bh[tt], acc[tt], 0, 0, 0);
#pragma unroll
        for (int tt = 0; tt < 4; tt++)
            acc[tt] = __builtin_amdgcn_mfma_f32_16x16x32_f16(al, bl[tt], acc[tt], 0, 0, 0);

#pragma unroll
        for (int tt = 0; tt < 4; tt++)
#pragma unroll
            for (int r = 0; r < 4; r++) {
                const float v = acc[tt][r];
                if (v > best[tt]) { best[tt] = v; bidx[tt] = code + r; }
            }
        code += 16;
    }

    // reduce across the 4 quads holding the same position (xor 16, 32)
#pragma unroll
    for (int off = 16; off < 64; off <<= 1) {
#pragma unroll
        for (int tt = 0; tt < 4; tt++) {
            const float ov = __shfl_xor(best[tt], off);
            const int   oi = __shfl_xor(bidx[tt], off);
            if (ov > best[tt] || (ov == best[tt] && oi < bidx[tt])) {
                best[tt] = ov; bidx[tt] = oi;
            }
        }
    }
    if (quad == 0) {
#pragma unroll
        for (int tt = 0; tt < 4; tt++) {
            pval[(size_t)chunk * P_TOTAL + wp0 + tt * 16 + col] = best[tt];
            pidx[(size_t)chunk * P_TOTAL + wp0 + tt * 16 + col] = bidx[tt];
        }
    }
}

// ---------------------------------------------------------------------------
// Kernel D: combine chunk partials (ascending k keeps lowest index on ties),
// histogram via atomics, quantization-loss partial sum. 256 blocks x 64 thr.
// ---------------------------------------------------------------------------
__global__ __launch_bounds__(64) void combine_kernel(
    const float* __restrict__ pval, const int* __restrict__ pidx,
    const float* __restrict__ z, const float* __restrict__ invz,
    const float* __restrict__ en,
    int* __restrict__ idx, int* __restrict__ hist, float* __restrict__ scalarAcc)
{
    const int p = blockIdx.x * 64 + threadIdx.x;
    float best = -3e38f;
    int   bi   = 0;
#pragma unroll
    for (int k = 0; k < NCHUNK; k++) {
        const float v = pval[k * P_TOTAL + p];
        const int   i = pidx[k * P_TOTAL + p];
        if (v > best) { best = v; bi = i; }
    }
    idx[p] = bi;
    atomicAdd(&hist[bi], 1);

    const float iv = invz[p];
    const float4* zsrc = reinterpret_cast<const float4*>(z + (size_t)p * DD);
    const float4* esrc = reinterpret_cast<const float4*>(en + (size_t)bi * DD);
    float ls = 0.f;
#pragma unroll
    for (int q = 0; q < 8; q++) {
        const float4 zv = zsrc[q];
        const float4 ev = esrc[q];
        const float dx = zv.x * iv - ev.x;
        const float dy = zv.y * iv - ev.y;
        const float dz = zv.z * iv - ev.z;
        const float dw = zv.w * iv - ev.w;
        ls += dx * dx + dy * dy + dz * dz + dw * dw;
    }
    __shared__ float red[64];
    red[threadIdx.x] = ls;
    __syncthreads();
    for (int s = 32; s > 0; s >>= 1) {
        if (threadIdx.x < s) red[threadIdx.x] += red[threadIdx.x + s];
        __syncthreads();
    }
    if (threadIdx.x == 0) atomicAdd(&scalarAcc[0], red[0]);
}

// ---------------------------------------------------------------------------
// Kernel E: out[b][c][hw] = sum_d en[idx[p]][d] * exp_w[c][d] + exp_b[c]
// Grid 512 = 256 position-groups x 2 c-halves. cg wave-uniform via
// readfirstlane -> ew loads are s_loads. latents in LDS (pad 33),
// stores coalesced along hw.
// ---------------------------------------------------------------------------
__global__ __launch_bounds__(256) void expand_kernel(
    const int* __restrict__ idx, const float* __restrict__ en,
    const float* __restrict__ ew, const float* __restrict__ eb,
    float* __restrict__ out)
{
    const int t     = threadIdx.x;
    const int chalf = blockIdx.x & 1;
    const int pg    = blockIdx.x >> 1;
    const int p0    = pg * 64;
    const int b     = p0 >> 10;
    const int hw0   = p0 & 1023;

    __shared__ float lat[64 * 33];
    for (int i = t; i < 64 * DD; i += 256) {
        const int pl = i >> 5, d = i & 31;
        lat[pl * 33 + d] = en[(size_t)idx[p0 + pl] * DD + d];
    }
    __syncthreads();

    const int hw_l = t & 63;
    const int cg   = __builtin_amdgcn_readfirstlane(t >> 6);   // SGPR-uniform
    float lr[32];
#pragma unroll
    for (int d = 0; d < DD; d++) lr[d] = lat[hw_l * 33 + d];

    float* outb = out + (size_t)b * (CCH * HWSZ) + hw0 + hw_l;
    const int c0 = chalf * 256 + cg * 64;
#pragma unroll 4
    for (int k = 0; k < 64; k++) {
        const int c = c0 + k;
        const float* ewc = ew + (size_t)c * DD;      // uniform -> s_load
        float s0 = 0.f, s1 = 0.f, s2 = 0.f, s3 = 0.f;
#pragma unroll
        for (int d = 0; d < DD; d += 4) {
            s0 = fmaf(lr[d + 0], ewc[d + 0], s0);
            s1 = fmaf(lr[d + 1], ewc[d + 1], s1);
            s2 = fmaf(lr[d + 2], ewc[d + 2], s2);
            s3 = fmaf(lr[d + 3], ewc[d + 3], s3);
        }
        outb[(size_t)c * HWSZ] = (s0 + s1) + (s2 + s3) + eb[c];
    }
}

// ---------------------------------------------------------------------------
// Kernel F1: entropy partials — 64 blocks x 256 thr, one hist element each
// (R4's single-block final_kernel serialized 64 dependent loads/thread).
// ---------------------------------------------------------------------------
__global__ __launch_bounds__(256) void entropy_kernel(
    const int* __restrict__ hist, float* __restrict__ scalarAcc)
{
    const int i = blockIdx.x * 256 + threadIdx.x;
    const float u = (float)hist[i] * (1.f / (float)P_TOTAL);
    float h = -u * logf(u + 1e-6f);
    __shared__ float red[256];
    red[threadIdx.x] = h;
    __syncthreads();
    for (int s = 128; s > 0; s >>= 1) {
        if (threadIdx.x < s) red[threadIdx.x] += red[threadIdx.x + s];
        __syncthreads();
    }
    if (threadIdx.x == 0) atomicAdd(&scalarAcc[1], red[0]);
}

// ---------------------------------------------------------------------------
// Kernel F2: write the two scalar outputs.
// ---------------------------------------------------------------------------
__global__ __launch_bounds__(64) void scalar_kernel(
    const float* __restrict__ scalarAcc, float* __restrict__ out_scalars)
{
    if (threadIdx.x == 0) {
        out_scalars[0] = scalarAcc[0] * (1.f / (float)(P_TOTAL * DD));  // mean
        out_scalars[1] = expf(scalarAcc[1]);
    }
}

// ---------------------------------------------------------------------------
// Workspace layout (bytes):
//   z      @ 0        : 16384*32*4  = 2,097,152
//   invz   @ 2097152  : 16384*4     =    65,536
//   en     @ 2162688  : 16384*32*4  = 2,097,152
//   zf16   @ 4259840  : 16384*128   = 2,097,152  (hi|lo f16 rows, x4096)
//   ef16   @ 6356992  : 16384*128   = 2,097,152
//   pval   @ 8454144  : 16*16384*4  = 1,048,576
//   pidx   @ 9502720  : 16*16384*4  = 1,048,576
//   idx    @ 10551296 : 16384*4     =    65,536
//   hist   @ 10616832 : 16384*4     =    65,536
//   scalarAcc @ 10682368 : 2*4      (loss, entropy)   (total ~10.7 MB)
// ---------------------------------------------------------------------------
extern "C" void kernel_launch(void* const* d_in, const int* in_sizes, int n_in,
                              void* d_out, int out_size, void* d_ws, size_t ws_size,
                              hipStream_t stream)
{
    const float* enc = (const float*)d_in[0];   // [16,512,32,32]
    const float* emb = (const float*)d_in[1];   // [16384,32]
    const float* pw  = (const float*)d_in[2];   // [32,512]
    const float* pb  = (const float*)d_in[3];   // [32]
    const float* ew  = (const float*)d_in[4];   // [512,32]
    const float* eb  = (const float*)d_in[5];   // [512]
    float* out = (float*)d_out;                 // 8388608 + loss + perplexity

    char* ws = (char*)d_ws;
    float* z         = (float*)(ws + 0);
    float* invz      = (float*)(ws + 2097152);
    float* en        = (float*)(ws + 2162688);
    char*  zf16      = ws + 4259840;
    char*  ef16      = ws + 6356992;
    float* pval      = (float*)(ws + 8454144);
    int*   pidx      = (int*)  (ws + 9502720);
    int*   idx       = (int*)  (ws + 10551296);
    int*   hist      = (int*)  (ws + 10616832);
    float* scalarAcc = (float*)(ws + 10682368);

    prep_kernel   <<<384, 256, 0, stream>>>(enc, pw, pb, emb, z, invz, zf16,
                                            en, ef16, hist, scalarAcc);
    argmax_kernel <<<64 * NCHUNK, 256, 0, stream>>>(zf16, ef16, pval, pidx);
    combine_kernel<<<P_TOTAL / 64, 64, 0, stream>>>(pval, pidx, z, invz, en,
                                                    idx, hist, scalarAcc);
    entropy_kernel<<<NCODES / 256, 256, 0, stream>>>(hist, scalarAcc);
    expand_kernel <<<512, 256, 0, stream>>>(idx, en, ew, eb, out);
    scalar_kernel <<<1, 64, 0, stream>>>(scalarAcc, out + 8388608);
}

// Round 7
// 252.189 us; speedup vs baseline: 2.4077x; 1.0011x over previous
//
#include <hip/hip_runtime.h>
#include <cstdint>

// Problem constants (from reference setup_inputs)
#define BATCH   16
#define CCH     512
#define DD      32
#define NCODES  16384
#define HWSZ    1024            // 32*32
#define P_TOTAL 16384           // BATCH * HWSZ
#define NCHUNK  32
#define CHUNK   (NCODES / NCHUNK)   // 512 codes per chunk

typedef _Float16 half8 __attribute__((ext_vector_type(8)));
typedef float    f32x4 __attribute__((ext_vector_type(4)));

union H8 { _Float16 h[8]; uint4 u; };
union L8 { uint4 u; half8 h; };

// f16 split row layout: row = 128 B = [32 f16 hi | 32 f16 lo], values scaled
// by 2^12 so lo-terms stay in f16 normal range. sim accumulates at scale
// 2^24; argmax is scale-invariant. 4 exact product terms -> ~2^-22 rel err.

// ---------------------------------------------------------------------------
// Kernel PREP (fused): grid 384 blocks x 256 thr.
//   blocks [0,256):  proj  z[p][d] = sum_c enc*pw + pb, invz, zf16 split rows
//                    (c-loop explicitly double-buffered: 16 loads in flight
//                     while FMAs run on the previous 16)
//   blocks [256,320): enorm en rows + ef16 split rows
//   blocks [320,384): zero hist + scalarAcc (loss, entropy, done-counter)
// ---------------------------------------------------------------------------
__global__ __launch_bounds__(256) void prep_kernel(
    const float* __restrict__ enc, const float* __restrict__ pw,
    const float* __restrict__ pb, const float* __restrict__ emb,
    float* __restrict__ z, float* __restrict__ invz, char* __restrict__ zf16,
    float* __restrict__ en, char* __restrict__ ef16,
    int* __restrict__ hist, float* __restrict__ scalarAcc)
{
    const int t = threadIdx.x;

    if (blockIdx.x >= 320) {                 // ---- hist/scalar zeroing ----
        const int i = (blockIdx.x - 320) * 256 + t;
        hist[i] = 0;
        if (blockIdx.x == 320 && t < 4) scalarAcc[t] = 0.f;
        return;
    }

    if (blockIdx.x >= 256) {                 // ---- enorm ----
        const int r = (blockIdx.x - 256) * 256 + t;
        const float4* src = reinterpret_cast<const float4*>(emb + (size_t)r * DD);
        float4 v[8];
        float ssq = 0.f;
#pragma unroll
        for (int q = 0; q < 8; q++) {
            v[q] = src[q];
            ssq += v[q].x * v[q].x + v[q].y * v[q].y + v[q].z * v[q].z + v[q].w * v[q].w;
        }
        const float inv = 1.f / fmaxf(sqrtf(ssq), 1e-6f);
        float4* dst = reinterpret_cast<float4*>(en + (size_t)r * DD);
        char* row = ef16 + (size_t)r * 128;
#pragma unroll
        for (int q = 0; q < 8; q += 2) {
            H8 hi, lo;
#pragma unroll
            for (int u = 0; u < 2; u++) {
                float4 o;
                o.x = v[q + u].x * inv; o.y = v[q + u].y * inv;
                o.z = v[q + u].z * inv; o.w = v[q + u].w * inv;
                dst[q + u] = o;
                const float s[4] = {o.x * 4096.f, o.y * 4096.f, o.z * 4096.f, o.w * 4096.f};
#pragma unroll
                for (int j = 0; j < 4; j++) {
                    const _Float16 h = (_Float16)s[j];
                    hi.h[u * 4 + j] = h;
                    lo.h[u * 4 + j] = (_Float16)(s[j] - (float)h);
                }
            }
            *(uint4*)(row + q * 8)      = hi.u;
            *(uint4*)(row + 64 + q * 8) = lo.u;
        }
        return;
    }

    // ---- proj ----
    const int hw_l = t & 63;
    const int dg   = __builtin_amdgcn_readfirstlane(t >> 6);   // SGPR-uniform
    const int p0   = blockIdx.x * 64;
    const int b    = p0 >> 10;
    const int hw   = (p0 & 1023) + hw_l;
    const float* encb = enc + (size_t)b * (CCH * HWSZ) + hw;

    float acc[8];
#pragma unroll
    for (int j = 0; j < 8; j++) acc[j] = 0.f;

    float ev[16];
#pragma unroll
    for (int u = 0; u < 16; u++) ev[u] = encb[(size_t)u * HWSZ];

    for (int c0 = 0; c0 < CCH - 16; c0 += 16) {
        float nv[16];
#pragma unroll
        for (int u = 0; u < 16; u++)             // next batch in flight
            nv[u] = encb[(size_t)(c0 + 16 + u) * HWSZ];
#pragma unroll
        for (int u = 0; u < 16; u++)
#pragma unroll
            for (int j = 0; j < 8; j++)          // uniform -> s_load
                acc[j] = fmaf(ev[u], pw[(dg * 8 + j) * CCH + c0 + u], acc[j]);
#pragma unroll
        for (int u = 0; u < 16; u++) ev[u] = nv[u];
    }
#pragma unroll
    for (int u = 0; u < 16; u++)                 // final batch
#pragma unroll
        for (int j = 0; j < 8; j++)
            acc[j] = fmaf(ev[u], pw[(dg * 8 + j) * CCH + (CCH - 16) + u], acc[j]);

    const int p = p0 + hw_l;
    float ssq = 0.f;
    H8 hi, lo;
#pragma unroll
    for (int j = 0; j < 8; j++) {
        const float v = acc[j] + pb[dg * 8 + j];
        z[(size_t)p * DD + dg * 8 + j] = v;
        ssq = fmaf(v, v, ssq);
        const float vs = v * 4096.f;
        const _Float16 h = (_Float16)vs;
        hi.h[j] = h;
        lo.h[j] = (_Float16)(vs - (float)h);
    }
    char* row = zf16 + (size_t)p * 128;
    *(uint4*)(row + dg * 16)      = hi.u;
    *(uint4*)(row + 64 + dg * 16) = lo.u;

    __shared__ float red[4][64];
    red[dg][hw_l] = ssq;
    __syncthreads();
    if (t < 64) {
        const float tot = red[0][t] + red[1][t] + red[2][t] + red[3][t];
        invz[p0 + t] = 1.f / fmaxf(sqrtf(tot), 1e-6f);
    }
}

// ---------------------------------------------------------------------------
// Kernel C: fused MFMA sims + argmax over one 512-code chunk.
// R6: 2048 blocks (8/CU -> 2x resident waves), 2-tile-deep prefetch (4 loads
// in flight covers ~400cyc L2 latency), XCD-locality chunk swizzle
// (chunk = (b&7)*4 + (b>>9): each XCD touches 4 chunks = 512KB of ef16).
// 64 positions/wave, hi/lo terms folded into one depth-4 MFMA chain per
// pos-tile via the C operand; 4 chains interleaved.
// D layout: code=(lane>>4)*4+reg, pos=lane&15; shfl_xor(16,32) reduce with
// equal->lower-idx tie-break (numpy first-occurrence).
// ---------------------------------------------------------------------------
__global__ __launch_bounds__(256, 4) void argmax_kernel(
    const char* __restrict__ zf16, const char* __restrict__ ef16,
    float* __restrict__ pval, int* __restrict__ pidx)
{
    const int w    = threadIdx.x >> 6;       // wave 0..3
    const int lane = threadIdx.x & 63;
    const int col  = lane & 15;
    const int quad = lane >> 4;
    const int chunk = (blockIdx.x & 7) * 4 + (blockIdx.x >> 9);  // XCD swizzle
    const int pg    = (blockIdx.x >> 3) & 63;
    const int wp0   = pg * 256 + w * 64;     // wave position base (64 pos)

    // B fragments (z): pos-tile tt rows wp0 + tt*16 + col
    half8 bh[4], bl[4];
#pragma unroll
    for (int tt = 0; tt < 4; tt++) {
        const char* r = zf16 + (size_t)(wp0 + tt * 16 + col) * 128 + quad * 16;
        L8 a; a.u = *(const uint4*)(r);       bh[tt] = a.h;
        L8 b; b.u = *(const uint4*)(r + 64);  bl[tt] = b.h;
    }

    const int n0 = chunk * CHUNK;
    const char* abase = ef16 + (size_t)(n0 + col) * 128 + quad * 16;

    float best[4] = {-3e38f, -3e38f, -3e38f, -3e38f};
    int   bidx[4] = {0, 0, 0, 0};
    int   code = n0 + quad * 4;              // this lane's reg-0 code of tile 0

    // 2-tile-deep prefetch pipeline
    uint4 p0h = *(const uint4*)(abase);
    uint4 p0l = *(const uint4*)(abase + 64);
    uint4 p1h = *(const uint4*)(abase + 2048);
    uint4 p1l = *(const uint4*)(abase + 2048 + 64);
    const f32x4 zero4 = {0.f, 0.f, 0.f, 0.f};

    for (int tile = 0; tile < CHUNK / 16; tile++) {
        L8 ahu, alu;
        ahu.u = p0h;
        alu.u = p0l;
        p0h = p1h; p0l = p1l;
        // prefetch tile+2 (last iters over-read <5KB into pval region: safe)
        const char* nxt = abase + (size_t)(tile + 2) * 2048;
        p1h = *(const uint4*)(nxt);
        p1l = *(const uint4*)(nxt + 64);

        const half8 ah = ahu.h, al = alu.h;

        // 4 independent depth-4 chains (hh -> hl -> lh -> ll via C operand)
        f32x4 acc[4];
#pragma unroll
        for (int tt = 0; tt < 4; tt++)
            acc[tt] = __builtin_amdgcn_mfma_f32_16x16x32_f16(ah, bh[tt], zero4, 0, 0, 0);
#pragma unroll
        for (int tt = 0; tt < 4; tt++)
            acc[tt] = __builtin_amdgcn_mfma_f32_16x16x32_f16(ah, bl[tt], acc[tt], 0, 0, 0);
#pragma unroll
        for (int tt = 0; tt < 4; tt++)
            acc[tt] = __builtin_amdgcn_mfma_f32_16x16x32_f16(al, bh[tt], acc[tt], 0, 0, 0);
#pragma unroll
        for (int tt = 0; tt < 4; tt++)
            acc[tt] = __builtin_amdgcn_mfma_f32_16x16x32_f16(al, bl[tt], acc[tt], 0, 0, 0);

#pragma unroll
        for (int tt = 0; tt < 4; tt++)
#pragma unroll
            for (int r = 0; r < 4; r++) {
                const float v = acc[tt][r];
                if (v > best[tt]) { best[tt] = v; bidx[tt] = code + r; }
            }
        code += 16;
    }

    // reduce across the 4 quads holding the same position (xor 16, 32)
#pragma unroll
    for (int off = 16; off < 64; off <<= 1) {
#pragma unroll
        for (int tt = 0; tt < 4; tt++) {
            const float ov = __shfl_xor(best[tt], off);
            const int   oi = __shfl_xor(bidx[tt], off);
            if (ov > best[tt] || (ov == best[tt] && oi < bidx[tt])) {
                best[tt] = ov; bidx[tt] = oi;
            }
        }
    }
    if (quad == 0) {
#pragma unroll
        for (int tt = 0; tt < 4; tt++) {
            pval[(size_t)chunk * P_TOTAL + wp0 + tt * 16 + col] = best[tt];
            pidx[(size_t)chunk * P_TOTAL + wp0 + tt * 16 + col] = bidx[tt];
        }
    }
}

// ---------------------------------------------------------------------------
// Kernel COMBEX (fused combine + expand): 256 blocks x 512 thr, 64 pos each.
// Phase 1 (all 8 waves): per-position partial argmax over 4 chunks/kgroup.
// Phase 2 (wave 0): finalize argmax (idx-compare tie-break = lowest code on
// equal value, correct since chunk idx ranges are ordered), hist atomic,
// quantization-loss (shfl-reduced), stage en[idx] rows into LDS.
// Phase 3 (all): out[b][c][hw] = lat . exp_w[c] + exp_b[c]; ew via s_load.
// idx never round-trips through global memory.
// ---------------------------------------------------------------------------
__global__ __launch_bounds__(512) void combex_kernel(
    const float* __restrict__ pval, const int* __restrict__ pidx,
    const float* __restrict__ z, const float* __restrict__ invz,
    const float* __restrict__ en, const float* __restrict__ ew,
    const float* __restrict__ eb,
    int* __restrict__ hist, float* __restrict__ scalarAcc,
    float* __restrict__ out)
{
    const int t  = threadIdx.x;
    const int p0 = blockIdx.x * 64;

    __shared__ float lat[64 * 33];
    __shared__ float bvs[8][64];
    __shared__ int   bis[8][64];

    {   // phase 1: 8 kgroups x 4 chunks, ascending k (strict > = lowest k)
        const int pl = t & 63;
        const int kg = t >> 6;
        const int p  = p0 + pl;
        float best = -3e38f;
        int   bi   = 0;
#pragma unroll
        for (int k = 0; k < 4; k++) {
            const float v = pval[(size_t)(kg * 4 + k) * P_TOTAL + p];
            const int   i = pidx[(size_t)(kg * 4 + k) * P_TOTAL + p];
            if (v > best) { best = v; bi = i; }
        }
        bvs[kg][pl] = best;
        bis[kg][pl] = bi;
    }
    __syncthreads();

    if (t < 64) {   // phase 2 (wave 0)
        float best = bvs[0][t];
        int   bi   = bis[0][t];
#pragma unroll
        for (int kg = 1; kg < 8; kg++) {
            const float v = bvs[kg][t];
            const int   i = bis[kg][t];
            if (v > best || (v == best && i < bi)) { best = v; bi = i; }
        }
        const int p = p0 + t;
        atomicAdd(&hist[bi], 1);

        const float iv = invz[p];
        const float4* zsrc = reinterpret_cast<const float4*>(z + (size_t)p * DD);
        const float4* esrc = reinterpret_cast<const float4*>(en + (size_t)bi * DD);
        float ls = 0.f;
#pragma unroll
        for (int q = 0; q < 8; q++) {
            const float4 zv = zsrc[q];
            const float4 ev = esrc[q];
            lat[t * 33 + q * 4 + 0] = ev.x;
            lat[t * 33 + q * 4 + 1] = ev.y;
            lat[t * 33 + q * 4 + 2] = ev.z;
            lat[t * 33 + q * 4 + 3] = ev.w;
            const float dx = zv.x * iv - ev.x;
            const float dy = zv.y * iv - ev.y;
            const float dz = zv.z * iv - ev.z;
            const float dw = zv.w * iv - ev.w;
            ls += dx * dx + dy * dy + dz * dz + dw * dw;
        }
#pragma unroll
        for (int off = 32; off > 0; off >>= 1) ls += __shfl_down(ls, off);
        if (t == 0) atomicAdd(&scalarAcc[0], ls);
    }
    __syncthreads();

    // phase 3: expand — 8 waves x 64 c each
    const int hw_l = t & 63;
    const int cg   = __builtin_amdgcn_readfirstlane(t >> 6);   // 0..7
    float lr[32];
#pragma unroll
    for (int d = 0; d < DD; d++) lr[d] = lat[hw_l * 33 + d];

    const int b   = p0 >> 10;
    const int hw0 = p0 & 1023;
    float* outb = out + (size_t)b * (CCH * HWSZ) + hw0 + hw_l;
    const int c0 = cg * 64;
#pragma unroll 4
    for (int k = 0; k < 64; k++) {
        const int c = c0 + k;
        const float* ewc = ew + (size_t)c * DD;      // uniform -> s_load
        float s0 = 0.f, s1 = 0.f, s2 = 0.f, s3 = 0.f;
#pragma unroll
        for (int d = 0; d < DD; d += 4) {
            s0 = fmaf(lr[d + 0], ewc[d + 0], s0);
            s1 = fmaf(lr[d + 1], ewc[d + 1], s1);
            s2 = fmaf(lr[d + 2], ewc[d + 2], s2);
            s3 = fmaf(lr[d + 3], ewc[d + 3], s3);
        }
        outb[(size_t)c * HWSZ] = (s0 + s1) + (s2 + s3) + eb[c];
    }
}

// ---------------------------------------------------------------------------
// Kernel ENTROPY: 64 blocks x 256 thr, one hist element each. Last block
// (device-scope done-counter) finalizes both scalar outputs — agent-scope
// atomic loads dodge stale per-XCD L2 lines.
// ---------------------------------------------------------------------------
__global__ __launch_bounds__(256) void entropy_kernel(
    const int* __restrict__ hist, float* __restrict__ scalarAcc,
    float* __restrict__ out_scalars)
{
    const int i = blockIdx.x * 256 + threadIdx.x;
    const float u = (float)hist[i] * (1.f / (float)P_TOTAL);
    float h = -u * logf(u + 1e-6f);
    __shared__ float red[256];
    red[threadIdx.x] = h;
    __syncthreads();
    for (int s = 128; s > 0; s >>= 1) {
        if (threadIdx.x < s) red[threadIdx.x] += red[threadIdx.x + s];
        __syncthreads();
    }
    if (threadIdx.x == 0) {
        atomicAdd(&scalarAcc[1], red[0]);
        __threadfence();
        int* cnt = (int*)(scalarAcc + 2);
        const int prev = atomicAdd(cnt, 1);
        if (prev == 63) {    // last block: all adds are visible
            const float loss = __hip_atomic_load(&scalarAcc[0], __ATOMIC_RELAXED,
                                                 __HIP_MEMORY_SCOPE_AGENT);
            const float ent  = __hip_atomic_load(&scalarAcc[1], __ATOMIC_RELAXED,
                                                 __HIP_MEMORY_SCOPE_AGENT);
            out_scalars[0] = loss * (1.f / (float)(P_TOTAL * DD));
            out_scalars[1] = expf(ent);
        }
    }
}

// ---------------------------------------------------------------------------
// Workspace layout (bytes):
//   z      @ 0        : 16384*32*4  = 2,097,152
//   invz   @ 2097152  : 16384*4     =    65,536
//   en     @ 2162688  : 16384*32*4  = 2,097,152
//   zf16   @ 4259840  : 16384*128   = 2,097,152  (hi|lo f16 rows, x4096)
//   ef16   @ 6356992  : 16384*128   = 2,097,152
//   pval   @ 8454144  : 32*16384*4  = 2,097,152  (also argmax over-read pad)
//   pidx   @ 10551296 : 32*16384*4  = 2,097,152
//   hist   @ 12648448 : 16384*4     =    65,536
//   scalarAcc @ 12713984 : 4*4  (loss, entropy, done-counter, pad)
//   total ~12.7 MB
// ---------------------------------------------------------------------------
extern "C" void kernel_launch(void* const* d_in, const int* in_sizes, int n_in,
                              void* d_out, int out_size, void* d_ws, size_t ws_size,
                              hipStream_t stream)
{
    const float* enc = (const float*)d_in[0];   // [16,512,32,32]
    const float* emb = (const float*)d_in[1];   // [16384,32]
    const float* pw  = (const float*)d_in[2];   // [32,512]
    const float* pb  = (const float*)d_in[3];   // [32]
    const float* ew  = (const float*)d_in[4];   // [512,32]
    const float* eb  = (const float*)d_in[5];   // [512]
    float* out = (float*)d_out;                 // 8388608 + loss + perplexity

    char* ws = (char*)d_ws;
    float* z         = (float*)(ws + 0);
    float* invz      = (float*)(ws + 2097152);
    float* en        = (float*)(ws + 2162688);
    char*  zf16      = ws + 4259840;
    char*  ef16      = ws + 6356992;
    float* pval      = (float*)(ws + 8454144);
    int*   pidx      = (int*)  (ws + 10551296);
    int*   hist      = (int*)  (ws + 12648448);
    float* scalarAcc = (float*)(ws + 12713984);

    prep_kernel   <<<384, 256, 0, stream>>>(enc, pw, pb, emb, z, invz, zf16,
                                            en, ef16, hist, scalarAcc);
    argmax_kernel <<<64 * NCHUNK, 256, 0, stream>>>(zf16, ef16, pval, pidx);
    combex_kernel <<<P_TOTAL / 64, 512, 0, stream>>>(pval, pidx, z, invz, en,
                                                     ew, eb, hist, scalarAcc, out);
    entropy_kernel<<<NCODES / 256, 256, 0, stream>>>(hist, scalarAcc,
                                                     out + 8388608);
}